// Round 5
// baseline (357.328 us; speedup 1.0000x reference)
//
#include <hip/hip_runtime.h>

#define NN 100000
#define NE 1600000
#define KB 782      // coarse buckets: ceil(100000/128)
#define BSH 7       // bucket = dst >> 7; 128 nodes per bucket
#define MAXB 4096   // fixed slots per bucket (mean 2046, max ~2250 — safe)
#define PBLK 200    // cpart block-range; NE/PBLK = 8000 edges per block

// Workspace layout in 4-byte units:
#define OFF_CC    0            // 1024: per-bucket edge counts
#define OFF_RST   1024         // 100096: per-node edge-range start (global slot index)
#define OFF_RDG   101120       // 100096: per-node degree
#define OFF_STAGE 201216       // KB*MAXB: packed (dstLow<<17)|src; node-sorted src after sort_kernel
#define OFF_XB    3404288      // x bf16 [100096,128]
#define OFF_XF8   9810432      // x fp8 [100096,128]; pb bf16 [100096,64] aliases (xf8 dead after agg1s)
#define OFF_MEANB 13013504     // mean bf16 [100096,128]
#define OFF_W1LP  25825792     // packed weights bf16
#define OFF_W1RP  (25825792 + 8192)
#define OFF_W2LP  (25825792 + 16384)
#define OFF_W2RP  (25825792 + 20480)

typedef __bf16 bf16x8 __attribute__((ext_vector_type(8)));
typedef float f32x4 __attribute__((ext_vector_type(4)));
typedef float f32x2 __attribute__((ext_vector_type(2)));

static __device__ __forceinline__ ushort f2bf(float f) {
    unsigned u = __float_as_uint(f);
    return (ushort)((u + 0x7fffu + ((u >> 16) & 1u)) >> 16);
}
static __device__ __forceinline__ float bflo(unsigned u) { return __uint_as_float(u << 16); }
static __device__ __forceinline__ float bfhi(unsigned u) { return __uint_as_float(u & 0xffff0000u); }

// ---------------------------------------------------------------------------
// Fused prep (1024 threads/block): cpart [0,200) + pack [200,206) + cvt rest.
// ---------------------------------------------------------------------------
#define PREP_CPART 200
#define PREP_PACKB 6      // 6 blocks x 4 virtual = 24 pack sub-blocks
#define PREP_CVT   3125
#define PREP_GRID  (PREP_CPART + PREP_PACKB + PREP_CVT)

__global__ __launch_bounds__(1024) void prep_kernel(
    const float* __restrict__ x, ushort* __restrict__ xb, unsigned* __restrict__ xf8,
    const float* __restrict__ W1l, const float* __restrict__ W1r,
    const float* __restrict__ W2l, const float* __restrict__ W2r,
    ushort* __restrict__ w1lp, ushort* __restrict__ w1rp,
    ushort* __restrict__ w2lp, ushort* __restrict__ w2rp,
    const int* __restrict__ src, const int* __restrict__ dst,
    int* __restrict__ cc, unsigned* __restrict__ stage) {
    __shared__ int hist[KB];
    __shared__ int cur[KB];
    int bid = blockIdx.x;
    int t = threadIdx.x;

    if (bid >= PREP_CPART + PREP_PACKB) {
        int i = (bid - PREP_CPART - PREP_PACKB) * 1024 + t;  // [0, 3.2M)
        float4 v = ((const float4*)x)[i];
        uint2 o;
        o.x = (unsigned)f2bf(v.x) | ((unsigned)f2bf(v.y) << 16);
        o.y = (unsigned)f2bf(v.z) | ((unsigned)f2bf(v.w) << 16);
        ((uint2*)xb)[i] = o;
        int p8 = __builtin_amdgcn_cvt_pk_fp8_f32(v.x, v.y, 0, false);
        p8 = __builtin_amdgcn_cvt_pk_fp8_f32(v.z, v.w, p8, true);
        xf8[i] = (unsigned)p8;
        return;
    }

    if (bid >= PREP_CPART) {
        int vb = (bid - PREP_CPART) * 4 + (t >> 8);  // virtual 256-thread block [0,24)
        int vt = t & 255;
        const float* W;
        ushort* out;
        int N, frag0;
        if (vb < 8)       { W = W1l; out = w1lp; N = 128; frag0 = vb * 4; }
        else if (vb < 16) { W = W1r; out = w1rp; N = 128; frag0 = (vb - 8) * 4; }
        else if (vb < 20) { W = W2l; out = w2lp; N = 64;  frag0 = (vb - 16) * 4; }
        else              { W = W2r; out = w2rp; N = 64;  frag0 = (vb - 20) * 4; }
        int lane = vt & 63;
        int frag = frag0 + (vt >> 6);
        int NT = N >> 4;
        int ktile = frag / NT, ntile = frag - ktile * NT;
        int k = ktile * 32 + (lane >> 4) * 8;
        int n = ntile * 16 + (lane & 15);
        ushort tmp[8];
#pragma unroll
        for (int j = 0; j < 8; ++j) tmp[j] = f2bf(W[(k + j) * N + n]);
        uint4 o;
        o.x = (unsigned)tmp[0] | ((unsigned)tmp[1] << 16);
        o.y = (unsigned)tmp[2] | ((unsigned)tmp[3] << 16);
        o.z = (unsigned)tmp[4] | ((unsigned)tmp[5] << 16);
        o.w = (unsigned)tmp[6] | ((unsigned)tmp[7] << 16);
        *(uint4*)&out[(frag * 64 + lane) * 8] = o;
        return;
    }

    // ---- cpart: coarse partition, full 1024-thread blocks ----
    int e0 = bid * (NE / PBLK);
    int e1 = e0 + (NE / PBLK);
    for (int i = t; i < KB; i += 1024) hist[i] = 0;
    __syncthreads();
    for (int e = e0 + t; e < e1; e += 1024)
        atomicAdd(&hist[dst[e] >> BSH], 1);
    __syncthreads();
    for (int i = t; i < KB; i += 1024) {
        int c = hist[i];
        cur[i] = c ? atomicAdd(&cc[i], c) : 0;
    }
    __syncthreads();
    for (int e = e0 + t; e < e1; e += 1024) {
        int d = dst[e];
        int bkt = d >> BSH;
        int p = atomicAdd(&cur[bkt], 1);
        if (p < MAXB)
            stage[bkt * MAXB + p] = ((unsigned)(d & 127) << 17) | (unsigned)src[e];
    }
}

// ---------------------------------------------------------------------------
// Sort: one block per bucket. Build local CSR in LDS, write node-sorted src
// back into the stage slots, emit global rstart/rdeg.
// ---------------------------------------------------------------------------
__global__ __launch_bounds__(256) void sort_kernel(unsigned* __restrict__ stage,
                                                   const int* __restrict__ cc,
                                                   int* __restrict__ rstart,
                                                   int* __restrict__ rdeg) {
    __shared__ unsigned ssrc[MAXB];
    __shared__ int sc[128];
    __shared__ int loff[129];
    __shared__ int lcur[128];
    int t = threadIdx.x;
    int b = blockIdx.x;
    unsigned* st = stage + b * MAXB;
    int cnt = min(cc[b], MAXB);

    if (t < 128) lcur[t] = 0;
    __syncthreads();
    for (int i = t; i < cnt; i += 256) atomicAdd(&lcur[st[i] >> 17], 1);
    __syncthreads();
    if (t < 128) sc[t] = lcur[t];
    __syncthreads();
    for (int off = 1; off < 128; off <<= 1) {
        int v = (t < 128 && t >= off) ? sc[t - off] : 0;
        __syncthreads();
        if (t < 128) sc[t] += v;
        __syncthreads();
    }
    if (t < 128) {
        int excl = (t == 0) ? 0 : sc[t - 1];
        loff[t] = excl;
        lcur[t] = excl;
    }
    if (t == 127) loff[128] = sc[127];
    __syncthreads();
    for (int i = t; i < cnt; i += 256) {
        unsigned v = st[i];
        int p = atomicAdd(&lcur[v >> 17], 1);
        ssrc[p] = v & 0x1FFFFu;
    }
    __syncthreads();
    for (int i = t; i < cnt; i += 256) st[i] = ssrc[i];
    int node0 = b << BSH;
    if (t < 128 && node0 + t < NN) {
        rstart[node0 + t] = b * MAXB + loff[t];
        rdeg[node0 + t] = loff[t + 1] - loff[t];
    }
}

// ---------------------------------------------------------------------------
// XCD-SLICED gathers. Tables are 128 B/row; 4 channel-slices of 32 B each.
// slice = blockIdx & 3. MI355X dispatches blocks round-robin over 8 XCDs
// (XCD = bid % 8), and 4 | 8, so every XCD touches exactly ONE slice ->
// gather working set per XCD = 12.8/4 = 3.2 MB < 4 MiB L2 -> gathers become
// L2 hits instead of ~900-cycle HBM misses. Edge list is re-read 4x
// (nontemporal, streams through without evicting the hot slice) and staged
// in LDS per block (contiguous range thanks to sort_kernel), so the inner
// loop issues ONLY gather loads. 4 lanes/node x uint2 = coalesced 32 B/edge.
// Grid: 1563 node-groups x 4 slices = 6252 blocks, 64 nodes/block.
// ---------------------------------------------------------------------------
#define AGG_NPB  64
#define AGG_NGRP ((NN + AGG_NPB - 1) / AGG_NPB)   // 1563
#define AGG_GRID (AGG_NGRP * 4)

static __device__ __forceinline__ void accum8(float* a, uint2 u) {
    f32x2 p0 = __builtin_amdgcn_cvt_pk_f32_fp8(u.x, false);
    f32x2 p1 = __builtin_amdgcn_cvt_pk_f32_fp8(u.x, true);
    f32x2 p2 = __builtin_amdgcn_cvt_pk_f32_fp8(u.y, false);
    f32x2 p3 = __builtin_amdgcn_cvt_pk_f32_fp8(u.y, true);
    a[0] += p0.x; a[1] += p0.y; a[2] += p1.x; a[3] += p1.y;
    a[4] += p2.x; a[5] += p2.y; a[6] += p3.x; a[7] += p3.y;
}

__global__ __launch_bounds__(256) void agg1s_kernel(const unsigned* __restrict__ es,
                                                    const int* __restrict__ rstart,
                                                    const int* __restrict__ rdeg,
                                                    const unsigned* __restrict__ xf8,
                                                    ushort* __restrict__ meanb) {
    __shared__ unsigned eidx[MAXB];
    int t = threadIdx.x;
    int s = blockIdx.x & 3;
    int node0 = (blockIdx.x >> 2) * AGG_NPB;
    int nodeL = min(node0 + AGG_NPB - 1, NN - 1);
    int eBase = rstart[node0];
    int cnt = rstart[nodeL] + rdeg[nodeL] - eBase;
    for (int i = t; i < cnt; i += 256)
        eidx[i] = __builtin_nontemporal_load(&es[eBase + i]);
    __syncthreads();

    int node = node0 + (t >> 2);
    int l2 = t & 3;
    int s0 = 0, deg = 0;
    if (node < NN) { s0 = rstart[node] - eBase; deg = rdeg[node]; }
    const uint2* xv = (const uint2*)xf8;  // row = 16 uint2 (128 fp8)
    int sb = s * 4 + l2;                  // lane's uint2 within the row
    float a[8] = {0.f, 0.f, 0.f, 0.f, 0.f, 0.f, 0.f, 0.f};
    int e = 0;
    for (; e + 4 <= deg; e += 4) {
        int q0 = eidx[s0 + e + 0], q1 = eidx[s0 + e + 1];
        int q2 = eidx[s0 + e + 2], q3 = eidx[s0 + e + 3];
        uint2 u0 = xv[q0 * 16 + sb];
        uint2 u1 = xv[q1 * 16 + sb];
        uint2 u2 = xv[q2 * 16 + sb];
        uint2 u3 = xv[q3 * 16 + sb];
        accum8(a, u0); accum8(a, u1); accum8(a, u2); accum8(a, u3);
    }
    for (; e < deg; ++e) accum8(a, xv[eidx[s0 + e] * 16 + sb]);

    if (node < NN) {
        float inv = 1.0f / fmaxf((float)deg, 1.0f);
        uint4 o;
        o.x = (unsigned)f2bf(a[0] * inv) | ((unsigned)f2bf(a[1] * inv) << 16);
        o.y = (unsigned)f2bf(a[2] * inv) | ((unsigned)f2bf(a[3] * inv) << 16);
        o.z = (unsigned)f2bf(a[4] * inv) | ((unsigned)f2bf(a[5] * inv) << 16);
        o.w = (unsigned)f2bf(a[6] * inv) | ((unsigned)f2bf(a[7] * inv) << 16);
        // channel offset = s*32 + l2*8 (ushort units within the 128-ch row)
        *(uint4*)&meanb[(size_t)node * 128 + s * 32 + l2 * 8] = o;
    }
}

__global__ __launch_bounds__(256) void agg2s_kernel(const unsigned* __restrict__ es,
                                                    const int* __restrict__ rstart,
                                                    const int* __restrict__ rdeg,
                                                    const ushort* __restrict__ pb,
                                                    float* __restrict__ out) {
    __shared__ unsigned eidx[MAXB];
    int t = threadIdx.x;
    int s = blockIdx.x & 3;
    int node0 = (blockIdx.x >> 2) * AGG_NPB;
    int nodeL = min(node0 + AGG_NPB - 1, NN - 1);
    int eBase = rstart[node0];
    int cnt = rstart[nodeL] + rdeg[nodeL] - eBase;
    for (int i = t; i < cnt; i += 256)
        eidx[i] = __builtin_nontemporal_load(&es[eBase + i]);
    __syncthreads();

    int node = node0 + (t >> 2);
    int l2 = t & 3;
    int s0 = 0, deg = 0;
    if (node < NN) { s0 = rstart[node] - eBase; deg = rdeg[node]; }
    // Coalesced partial-out read issued early (slice = 16 fp32 ch -> 4/lane).
    f32x4 p = {0.f, 0.f, 0.f, 0.f};
    size_t obase = (size_t)node * 64 + s * 16 + l2 * 4;
    if (node < NN) p = *(const f32x4*)&out[obase];

    const uint2* pv = (const uint2*)pb;   // row = 16 uint2 (64 bf16)
    int sb = s * 4 + l2;                  // lane's uint2 (4 bf16 ch) in the row
    float a0 = 0.f, a1 = 0.f, a2 = 0.f, a3 = 0.f;
    int e = 0;
    for (; e + 4 <= deg; e += 4) {
        int q0 = eidx[s0 + e + 0], q1 = eidx[s0 + e + 1];
        int q2 = eidx[s0 + e + 2], q3 = eidx[s0 + e + 3];
        uint2 u0 = pv[q0 * 16 + sb];
        uint2 u1 = pv[q1 * 16 + sb];
        uint2 u2 = pv[q2 * 16 + sb];
        uint2 u3 = pv[q3 * 16 + sb];
        a0 += bflo(u0.x) + bflo(u1.x) + bflo(u2.x) + bflo(u3.x);
        a1 += bfhi(u0.x) + bfhi(u1.x) + bfhi(u2.x) + bfhi(u3.x);
        a2 += bflo(u0.y) + bflo(u1.y) + bflo(u2.y) + bflo(u3.y);
        a3 += bfhi(u0.y) + bfhi(u1.y) + bfhi(u2.y) + bfhi(u3.y);
    }
    for (; e < deg; ++e) {
        uint2 u = pv[eidx[s0 + e] * 16 + sb];
        a0 += bflo(u.x); a1 += bfhi(u.x);
        a2 += bflo(u.y); a3 += bfhi(u.y);
    }
    if (node < NN) {
        float inv = 1.0f / fmaxf((float)deg, 1.0f);
        f32x4 o = {p.x + a0 * inv, p.y + a1 * inv, p.z + a2 * inv, p.w + a3 * inv};
        *(f32x4*)&out[obase] = o;
    }
}

// ---------------------------------------------------------------------------
// GEMM1 fused (MFMA): h = relu(mean@W1l + x@W1r + b1);
//   pb  = bf16(h@W2l)         (for the layer-2 gather)
//   out = h@W2r + b2          (partial final output; agg2s adds the mean)
// ---------------------------------------------------------------------------
__global__ __launch_bounds__(256) void gemm1_kernel(const ushort* __restrict__ meanb,
                                                    const ushort* __restrict__ xb,
                                                    const ushort* __restrict__ w1lp,
                                                    const ushort* __restrict__ w1rp,
                                                    const float* __restrict__ b1,
                                                    const ushort* __restrict__ w2lp,
                                                    const ushort* __restrict__ w2rp,
                                                    const float* __restrict__ b2,
                                                    ushort* __restrict__ pb,
                                                    float* __restrict__ out) {
    __shared__ ushort As[64 * 136];
    int t = threadIdx.x;
    int node0 = blockIdx.x * 64;
    int w = t >> 6, l = t & 63;
    int lrow = w * 16 + (l & 15);
    int lkq = (l >> 4) * 8;
    int cq = l & 15, rq = (l >> 4) * 4;

    f32x4 acc[8];
#pragma unroll
    for (int i = 0; i < 8; ++i) acc[i] = (f32x4){0.f, 0.f, 0.f, 0.f};

    {
        const uint4* g = (const uint4*)(meanb + (size_t)node0 * 128);
#pragma unroll
        for (int i = 0; i < 4; ++i) {
            int chunk = t + 256 * i;
            *(uint4*)&As[(chunk >> 4) * 136 + (chunk & 15) * 8] = g[chunk];
        }
    }
    __syncthreads();
#pragma unroll
    for (int kt = 0; kt < 4; ++kt) {
        bf16x8 a = *(const bf16x8*)&As[lrow * 136 + kt * 32 + lkq];
        const bf16x8* bp = (const bf16x8*)w1lp + (kt * 8) * 64 + l;
#pragma unroll
        for (int nt = 0; nt < 8; ++nt)
            acc[nt] = __builtin_amdgcn_mfma_f32_16x16x32_bf16(a, bp[nt * 64], acc[nt], 0, 0, 0);
    }
    __syncthreads();

    {
        const uint4* g = (const uint4*)(xb + (size_t)node0 * 128);
#pragma unroll
        for (int i = 0; i < 4; ++i) {
            int chunk = t + 256 * i;
            *(uint4*)&As[(chunk >> 4) * 136 + (chunk & 15) * 8] = g[chunk];
        }
    }
    __syncthreads();
#pragma unroll
    for (int kt = 0; kt < 4; ++kt) {
        bf16x8 a = *(const bf16x8*)&As[lrow * 136 + kt * 32 + lkq];
        const bf16x8* bp = (const bf16x8*)w1rp + (kt * 8) * 64 + l;
#pragma unroll
        for (int nt = 0; nt < 8; ++nt)
            acc[nt] = __builtin_amdgcn_mfma_f32_16x16x32_bf16(a, bp[nt * 64], acc[nt], 0, 0, 0);
    }
    __syncthreads();

    // h (relu + bias) back into As as bf16.
#pragma unroll
    for (int nt = 0; nt < 8; ++nt) {
        int n = nt * 16 + cq;
        float bias = b1[n];
#pragma unroll
        for (int r = 0; r < 4; ++r) {
            float hv = fmaxf(acc[nt][r] + bias, 0.0f);
            As[(w * 16 + rq + r) * 136 + n] = f2bf(hv);
        }
    }
    __syncthreads();

    // Both second-layer products from the same h fragments.
    f32x4 acc2[4];  // h@W2l -> pb
    f32x4 acc3[4];  // h@W2r -> partial out
#pragma unroll
    for (int i = 0; i < 4; ++i) {
        acc2[i] = (f32x4){0.f, 0.f, 0.f, 0.f};
        acc3[i] = (f32x4){0.f, 0.f, 0.f, 0.f};
    }
#pragma unroll
    for (int kt = 0; kt < 4; ++kt) {
        bf16x8 a = *(const bf16x8*)&As[lrow * 136 + kt * 32 + lkq];
        const bf16x8* bpl = (const bf16x8*)w2lp + (kt * 4) * 64 + l;
        const bf16x8* bpr = (const bf16x8*)w2rp + (kt * 4) * 64 + l;
#pragma unroll
        for (int nt = 0; nt < 4; ++nt) {
            acc2[nt] = __builtin_amdgcn_mfma_f32_16x16x32_bf16(a, bpl[nt * 64], acc2[nt], 0, 0, 0);
            acc3[nt] = __builtin_amdgcn_mfma_f32_16x16x32_bf16(a, bpr[nt * 64], acc3[nt], 0, 0, 0);
        }
    }

    // Partial out = h@W2r + b2, straight from accumulators.
#pragma unroll
    for (int nt = 0; nt < 4; ++nt) {
        int n = nt * 16 + cq;
        float bias = b2[n];
#pragma unroll
        for (int r = 0; r < 4; ++r) {
            int row = node0 + w * 16 + rq + r;
            if (row < NN)
                out[(size_t)row * 64 + n] = acc3[nt][r] + bias;
        }
    }

    // pb = bf16(h@W2l) via LDS repack for vectorized store.
    __syncthreads();
#pragma unroll
    for (int nt = 0; nt < 4; ++nt)
#pragma unroll
        for (int r = 0; r < 4; ++r)
            As[(w * 16 + rq + r) * 136 + nt * 16 + cq] = f2bf(acc2[nt][r]);
    __syncthreads();
    {
        uint4* g = (uint4*)(pb + (size_t)node0 * 64);
#pragma unroll
        for (int i = 0; i < 2; ++i) {
            int chunk = t + 256 * i;
            if (node0 + (chunk >> 3) < NN)
                g[chunk] = *(const uint4*)&As[(chunk >> 3) * 136 + (chunk & 7) * 8];
        }
    }
}

extern "C" void kernel_launch(void* const* d_in, const int* in_sizes, int n_in,
                              void* d_out, int out_size, void* d_ws, size_t ws_size,
                              hipStream_t stream) {
    const float* x   = (const float*)d_in[0];
    const int*   ei  = (const int*)d_in[1];
    const float* W1l = (const float*)d_in[2];
    const float* W1r = (const float*)d_in[3];
    const float* b1  = (const float*)d_in[4];
    const float* W2l = (const float*)d_in[5];
    const float* W2r = (const float*)d_in[6];
    const float* b2  = (const float*)d_in[7];

    const int* src = ei;
    const int* dst = ei + NE;

    int*      ws_i   = (int*)d_ws;
    int*      cc     = ws_i + OFF_CC;
    int*      rstart = ws_i + OFF_RST;
    int*      rdeg   = ws_i + OFF_RDG;
    unsigned* stage  = (unsigned*)(ws_i + OFF_STAGE);
    ushort*   xb     = (ushort*)(ws_i + OFF_XB);
    unsigned* xf8    = (unsigned*)(ws_i + OFF_XF8);
    ushort*   pb     = (ushort*)(ws_i + OFF_XF8);   // aliases xf8 (disjoint lifetime)
    ushort*   meanb  = (ushort*)(ws_i + OFF_MEANB);
    ushort*   w1lp   = (ushort*)(ws_i + OFF_W1LP);
    ushort*   w1rp   = (ushort*)(ws_i + OFF_W1RP);
    ushort*   w2lp   = (ushort*)(ws_i + OFF_W2LP);
    ushort*   w2rp   = (ushort*)(ws_i + OFF_W2RP);

    (void)hipMemsetAsync(cc, 0, 1024 * sizeof(int), stream);

    // Fused prep: cpart (1024-thread) + pack + cvt in one concurrent launch.
    prep_kernel<<<PREP_GRID, 1024, 0, stream>>>(
        x, xb, xf8, W1l, W1r, W2l, W2r, w1lp, w1rp, w2lp, w2rp, src, dst, cc, stage);
    sort_kernel<<<KB, 256, 0, stream>>>(stage, cc, rstart, rdeg);

    // Layer 1: XCD-sliced gather + fused GEMM (both second-layer products).
    agg1s_kernel<<<AGG_GRID, 256, 0, stream>>>(stage, rstart, rdeg, xf8, meanb);
    gemm1_kernel<<<(NN + 63) / 64, 256, 0, stream>>>(meanb, xb, w1lp, w1rp, b1,
                                                     w2lp, w2rp, b2, pb, (float*)d_out);

    // Layer 2: XCD-sliced gather of pb, mean, add into partial out.
    agg2s_kernel<<<AGG_GRID, 256, 0, stream>>>(stage, rstart, rdeg, pb, (float*)d_out);
}

// Round 6
// 263.794 us; speedup vs baseline: 1.3546x; 1.3546x over previous
//
#include <hip/hip_runtime.h>

#define NN 100000
#define NE 1600000
#define KB 782      // coarse buckets: ceil(100000/128)
#define BSH 7       // bucket = dst >> 7; 128 nodes per bucket
#define MAXB 4096   // fixed slots per bucket (mean 2046, max ~2250 — safe)
#define PBLK 200    // cpart block-range; NE/PBLK = 8000 edges per block

// Workspace layout in 4-byte units:
#define OFF_CC    0            // 1024: per-bucket edge counts
#define OFF_RST   1024         // 100096: per-node edge-range start (global slot index)
#define OFF_RDG   101120       // 100096: per-node degree
#define OFF_STAGE 201216       // KB*MAXB: packed (dstLow<<17)|src; node-sorted src after sort_kernel
#define OFF_XB    3404288      // x bf16 [100096,128]
#define OFF_XF8   9810432      // x fp8 [100096,128]; pb bf16 [100096,64] aliases (xf8 dead after agg1)
#define OFF_MEANB 13013504     // mean bf16 [100096,128]
#define OFF_XR    19419648     // xr = bf16(x@W1r) [100096,128] (old hb region, freed by gemm2 fusion)
#define OFF_W1LP  25825792     // packed weights bf16
#define OFF_W1RP  (25825792 + 8192)
#define OFF_W2LP  (25825792 + 16384)
#define OFF_W2RP  (25825792 + 20480)

typedef __bf16 bf16x8 __attribute__((ext_vector_type(8)));
typedef float f32x4 __attribute__((ext_vector_type(4)));
typedef float f32x2 __attribute__((ext_vector_type(2)));

static __device__ __forceinline__ ushort f2bf(float f) {
    unsigned u = __float_as_uint(f);
    return (ushort)((u + 0x7fffu + ((u >> 16) & 1u)) >> 16);
}
static __device__ __forceinline__ float bflo(unsigned u) { return __uint_as_float(u << 16); }
static __device__ __forceinline__ float bfhi(unsigned u) { return __uint_as_float(u & 0xffff0000u); }
static __device__ __forceinline__ float bfu(ushort s) { return __uint_as_float((unsigned)s << 16); }

// ---------------------------------------------------------------------------
// Fused prep (1024 threads/block): cpart [0,200) + pack [200,206) + cvt rest.
// ---------------------------------------------------------------------------
#define PREP_CPART 200
#define PREP_PACKB 6      // 6 blocks x 4 virtual = 24 pack sub-blocks
#define PREP_CVT   3125
#define PREP_GRID  (PREP_CPART + PREP_PACKB + PREP_CVT)

__global__ __launch_bounds__(1024) void prep_kernel(
    const float* __restrict__ x, ushort* __restrict__ xb, unsigned* __restrict__ xf8,
    const float* __restrict__ W1l, const float* __restrict__ W1r,
    const float* __restrict__ W2l, const float* __restrict__ W2r,
    ushort* __restrict__ w1lp, ushort* __restrict__ w1rp,
    ushort* __restrict__ w2lp, ushort* __restrict__ w2rp,
    const int* __restrict__ src, const int* __restrict__ dst,
    int* __restrict__ cc, unsigned* __restrict__ stage) {
    __shared__ int hist[KB];
    __shared__ int cur[KB];
    int bid = blockIdx.x;
    int t = threadIdx.x;

    if (bid >= PREP_CPART + PREP_PACKB) {
        int i = (bid - PREP_CPART - PREP_PACKB) * 1024 + t;  // [0, 3.2M)
        float4 v = ((const float4*)x)[i];
        uint2 o;
        o.x = (unsigned)f2bf(v.x) | ((unsigned)f2bf(v.y) << 16);
        o.y = (unsigned)f2bf(v.z) | ((unsigned)f2bf(v.w) << 16);
        ((uint2*)xb)[i] = o;
        int p8 = __builtin_amdgcn_cvt_pk_fp8_f32(v.x, v.y, 0, false);
        p8 = __builtin_amdgcn_cvt_pk_fp8_f32(v.z, v.w, p8, true);
        xf8[i] = (unsigned)p8;
        return;
    }

    if (bid >= PREP_CPART) {
        int vb = (bid - PREP_CPART) * 4 + (t >> 8);  // virtual 256-thread block [0,24)
        int vt = t & 255;
        const float* W;
        ushort* out;
        int N, frag0;
        if (vb < 8)       { W = W1l; out = w1lp; N = 128; frag0 = vb * 4; }
        else if (vb < 16) { W = W1r; out = w1rp; N = 128; frag0 = (vb - 8) * 4; }
        else if (vb < 20) { W = W2l; out = w2lp; N = 64;  frag0 = (vb - 16) * 4; }
        else              { W = W2r; out = w2rp; N = 64;  frag0 = (vb - 20) * 4; }
        int lane = vt & 63;
        int frag = frag0 + (vt >> 6);
        int NT = N >> 4;
        int ktile = frag / NT, ntile = frag - ktile * NT;
        int k = ktile * 32 + (lane >> 4) * 8;
        int n = ntile * 16 + (lane & 15);
        ushort tmp[8];
#pragma unroll
        for (int j = 0; j < 8; ++j) tmp[j] = f2bf(W[(k + j) * N + n]);
        uint4 o;
        o.x = (unsigned)tmp[0] | ((unsigned)tmp[1] << 16);
        o.y = (unsigned)tmp[2] | ((unsigned)tmp[3] << 16);
        o.z = (unsigned)tmp[4] | ((unsigned)tmp[5] << 16);
        o.w = (unsigned)tmp[6] | ((unsigned)tmp[7] << 16);
        *(uint4*)&out[(frag * 64 + lane) * 8] = o;
        return;
    }

    // ---- cpart: coarse partition, full 1024-thread blocks ----
    int e0 = bid * (NE / PBLK);
    int e1 = e0 + (NE / PBLK);
    for (int i = t; i < KB; i += 1024) hist[i] = 0;
    __syncthreads();
    for (int e = e0 + t; e < e1; e += 1024)
        atomicAdd(&hist[dst[e] >> BSH], 1);
    __syncthreads();
    for (int i = t; i < KB; i += 1024) {
        int c = hist[i];
        cur[i] = c ? atomicAdd(&cc[i], c) : 0;
    }
    __syncthreads();
    for (int e = e0 + t; e < e1; e += 1024) {
        int d = dst[e];
        int bkt = d >> BSH;
        int p = atomicAdd(&cur[bkt], 1);
        if (p < MAXB)
            stage[bkt * MAXB + p] = ((unsigned)(d & 127) << 17) | (unsigned)src[e];
    }
}

// ---------------------------------------------------------------------------
// Sort: one block per bucket. Build local CSR in LDS, write node-sorted src
// back into the stage slots, emit global rstart/rdeg.
// ---------------------------------------------------------------------------
__global__ __launch_bounds__(256) void sort_kernel(unsigned* __restrict__ stage,
                                                   const int* __restrict__ cc,
                                                   int* __restrict__ rstart,
                                                   int* __restrict__ rdeg) {
    __shared__ unsigned ssrc[MAXB];
    __shared__ int sc[128];
    __shared__ int loff[129];
    __shared__ int lcur[128];
    int t = threadIdx.x;
    int b = blockIdx.x;
    unsigned* st = stage + b * MAXB;
    int cnt = min(cc[b], MAXB);

    if (t < 128) lcur[t] = 0;
    __syncthreads();
    for (int i = t; i < cnt; i += 256) atomicAdd(&lcur[st[i] >> 17], 1);
    __syncthreads();
    if (t < 128) sc[t] = lcur[t];
    __syncthreads();
    for (int off = 1; off < 128; off <<= 1) {
        int v = (t < 128 && t >= off) ? sc[t - off] : 0;
        __syncthreads();
        if (t < 128) sc[t] += v;
        __syncthreads();
    }
    if (t < 128) {
        int excl = (t == 0) ? 0 : sc[t - 1];
        loff[t] = excl;
        lcur[t] = excl;
    }
    if (t == 127) loff[128] = sc[127];
    __syncthreads();
    for (int i = t; i < cnt; i += 256) {
        unsigned v = st[i];
        int p = atomicAdd(&lcur[v >> 17], 1);
        ssrc[p] = v & 0x1FFFFu;
    }
    __syncthreads();
    for (int i = t; i < cnt; i += 256) st[i] = ssrc[i];
    int node0 = b << BSH;
    if (t < 128 && node0 + t < NN) {
        rstart[node0 + t] = b * MAXB + loff[t];
        rdeg[node0 + t] = loff[t + 1] - loff[t];
    }
}

// ---------------------------------------------------------------------------
// Fused layer-1: gather blocks (3125, round-3 structure: 16 lanes/node,
// 2-node interleave) + co-dispatched x@W1r GEMM blocks (1563). The gather is
// latency-bound (VALUBusy ~35%, HBM ~35%); the GEMM blocks fill the idle
// issue slots, moving ~half of gemm1's MFMA work under the gather's shadow.
// Interleaved odd/even in the first 3126 blocks so both types co-reside.
// __launch_bounds__(256,8) pins VGPR <= 64 so gather occupancy stays 8 blk/CU.
// ---------------------------------------------------------------------------
#define A1_GATHER 3125
#define A1_GEMM   1563
#define A1_GRID   (A1_GATHER + A1_GEMM)

static __device__ __forceinline__ void accum8(float* a, uint2 u) {
    f32x2 p0 = __builtin_amdgcn_cvt_pk_f32_fp8(u.x, false);
    f32x2 p1 = __builtin_amdgcn_cvt_pk_f32_fp8(u.x, true);
    f32x2 p2 = __builtin_amdgcn_cvt_pk_f32_fp8(u.y, false);
    f32x2 p3 = __builtin_amdgcn_cvt_pk_f32_fp8(u.y, true);
    a[0] += p0.x; a[1] += p0.y; a[2] += p1.x; a[3] += p1.y;
    a[4] += p2.x; a[5] += p2.y; a[6] += p3.x; a[7] += p3.y;
}

static __device__ __forceinline__ void writeRow8(ushort* __restrict__ meanb, int node,
                                                 int l4, const float* a, int deg) {
    float inv = 1.0f / fmaxf((float)deg, 1.0f);
    uint4 o;
    o.x = (unsigned)f2bf(a[0] * inv) | ((unsigned)f2bf(a[1] * inv) << 16);
    o.y = (unsigned)f2bf(a[2] * inv) | ((unsigned)f2bf(a[3] * inv) << 16);
    o.z = (unsigned)f2bf(a[4] * inv) | ((unsigned)f2bf(a[5] * inv) << 16);
    o.w = (unsigned)f2bf(a[6] * inv) | ((unsigned)f2bf(a[7] * inv) << 16);
    *(uint4*)&meanb[node * 128 + 8 * l4] = o;
}

__global__ __launch_bounds__(256, 8) void agg1f_kernel(const unsigned* __restrict__ es,
                                                       const int* __restrict__ rstart,
                                                       const int* __restrict__ rdeg,
                                                       const unsigned* __restrict__ xf8,
                                                       ushort* __restrict__ meanb,
                                                       const ushort* __restrict__ xb,
                                                       const ushort* __restrict__ w1rp,
                                                       ushort* __restrict__ xrb) {
    __shared__ ushort As[64 * 136];
    int bid = blockIdx.x;
    int t = threadIdx.x;

    bool isGemm = (bid < 2 * A1_GEMM) && (bid & 1);
    if (isGemm) {
        // ---- x@W1r GEMM block -> xrb bf16 ----
        int node0 = (bid >> 1) * 64;
        int w = t >> 6, l = t & 63;
        int lrow = w * 16 + (l & 15);
        int lkq = (l >> 4) * 8;
        int cq = l & 15, rq = (l >> 4) * 4;

        {
            const uint4* g = (const uint4*)(xb + (size_t)node0 * 128);
#pragma unroll
            for (int i = 0; i < 4; ++i) {
                int chunk = t + 256 * i;
                *(uint4*)&As[(chunk >> 4) * 136 + (chunk & 15) * 8] = g[chunk];
            }
        }
        __syncthreads();
        f32x4 acc[8];
#pragma unroll
        for (int i = 0; i < 8; ++i) acc[i] = (f32x4){0.f, 0.f, 0.f, 0.f};
#pragma unroll
        for (int kt = 0; kt < 4; ++kt) {
            bf16x8 a = *(const bf16x8*)&As[lrow * 136 + kt * 32 + lkq];
            const bf16x8* bp = (const bf16x8*)w1rp + (kt * 8) * 64 + l;
#pragma unroll
            for (int nt = 0; nt < 8; ++nt)
                acc[nt] = __builtin_amdgcn_mfma_f32_16x16x32_bf16(a, bp[nt * 64], acc[nt], 0, 0, 0);
        }
        __syncthreads();
#pragma unroll
        for (int nt = 0; nt < 8; ++nt)
#pragma unroll
            for (int r = 0; r < 4; ++r)
                As[(w * 16 + rq + r) * 136 + nt * 16 + cq] = f2bf(acc[nt][r]);
        __syncthreads();
        {
            uint4* g = (uint4*)(xrb + (size_t)node0 * 128);
#pragma unroll
            for (int i = 0; i < 4; ++i) {
                int chunk = t + 256 * i;
                if (node0 + (chunk >> 4) < NN)
                    g[chunk] = *(const uint4*)&As[(chunk >> 4) * 136 + (chunk & 15) * 8];
            }
        }
        return;
    }

    // ---- gather block (round-3 agg1g) ----
    int gi = (bid < 2 * A1_GEMM) ? (bid >> 1) : (bid - A1_GEMM);
    int l4 = t & 15;
    int nA = gi * 32 + (t >> 4) * 2;
    int nB = nA + 1;
    int sA = rstart[nA], dA = rdeg[nA];
    int sB = rstart[nB], dB = rdeg[nB];
    const uint2* xv = (const uint2*)xf8;  // row = 16 uint2 (128 fp8)
    float aA[8] = {0.f, 0.f, 0.f, 0.f, 0.f, 0.f, 0.f, 0.f};
    float aB[8] = {0.f, 0.f, 0.f, 0.f, 0.f, 0.f, 0.f, 0.f};
    int eA = 0, eB = 0;
    while (eA + 4 <= dA && eB + 4 <= dB) {
        int qa0 = es[sA + eA + 0], qa1 = es[sA + eA + 1];
        int qa2 = es[sA + eA + 2], qa3 = es[sA + eA + 3];
        int qb0 = es[sB + eB + 0], qb1 = es[sB + eB + 1];
        int qb2 = es[sB + eB + 2], qb3 = es[sB + eB + 3];
        uint2 ua0 = xv[qa0 * 16 + l4], ua1 = xv[qa1 * 16 + l4];
        uint2 ua2 = xv[qa2 * 16 + l4], ua3 = xv[qa3 * 16 + l4];
        uint2 ub0 = xv[qb0 * 16 + l4], ub1 = xv[qb1 * 16 + l4];
        uint2 ub2 = xv[qb2 * 16 + l4], ub3 = xv[qb3 * 16 + l4];
        accum8(aA, ua0); accum8(aA, ua1); accum8(aA, ua2); accum8(aA, ua3);
        accum8(aB, ub0); accum8(aB, ub1); accum8(aB, ub2); accum8(aB, ub3);
        eA += 4; eB += 4;
    }
    for (; eA + 4 <= dA; eA += 4) {
        int q0 = es[sA + eA + 0], q1 = es[sA + eA + 1];
        int q2 = es[sA + eA + 2], q3 = es[sA + eA + 3];
        uint2 u0 = xv[q0 * 16 + l4], u1 = xv[q1 * 16 + l4];
        uint2 u2 = xv[q2 * 16 + l4], u3 = xv[q3 * 16 + l4];
        accum8(aA, u0); accum8(aA, u1); accum8(aA, u2); accum8(aA, u3);
    }
    for (; eA < dA; ++eA) accum8(aA, xv[es[sA + eA] * 16 + l4]);
    for (; eB + 4 <= dB; eB += 4) {
        int q0 = es[sB + eB + 0], q1 = es[sB + eB + 1];
        int q2 = es[sB + eB + 2], q3 = es[sB + eB + 3];
        uint2 u0 = xv[q0 * 16 + l4], u1 = xv[q1 * 16 + l4];
        uint2 u2 = xv[q2 * 16 + l4], u3 = xv[q3 * 16 + l4];
        accum8(aB, u0); accum8(aB, u1); accum8(aB, u2); accum8(aB, u3);
    }
    for (; eB < dB; ++eB) accum8(aB, xv[es[sB + eB] * 16 + l4]);

    writeRow8(meanb, nA, l4, aA, dA);
    writeRow8(meanb, nB, l4, aB, dB);
}

// ---------------------------------------------------------------------------
// Layer-2 gather + final combine (round-3 structure): gathers pb (bf16),
// means, then out[node] = partial_out + mean. 32 lanes/node, 2-node
// interleave. Grid 6250 x 256.
// ---------------------------------------------------------------------------
__global__ __launch_bounds__(256) void agg2g_kernel(const unsigned* __restrict__ es,
                                                    const int* __restrict__ rstart,
                                                    const int* __restrict__ rdeg,
                                                    const ushort* __restrict__ pb,
                                                    float* __restrict__ out) {
    int t = threadIdx.x;
    int l5 = t & 31;
    int nA = blockIdx.x * 16 + (t >> 5) * 2;
    int nB = nA + 1;
    int sA = rstart[nA], dA = rdeg[nA];
    int sB = rstart[nB], dB = rdeg[nB];
    float2 pA = *(const float2*)&out[(size_t)nA * 64 + 2 * l5];
    float2 pB = *(const float2*)&out[(size_t)nB * 64 + 2 * l5];
    const unsigned* pbu = (const unsigned*)pb;  // row = 32 uint (64 bf16)
    float a0 = 0.f, a1 = 0.f, b0 = 0.f, b1 = 0.f;
    int eA = 0, eB = 0;
    while (eA + 4 <= dA && eB + 4 <= dB) {
        int qa0 = es[sA + eA + 0], qa1 = es[sA + eA + 1];
        int qa2 = es[sA + eA + 2], qa3 = es[sA + eA + 3];
        int qb0 = es[sB + eB + 0], qb1 = es[sB + eB + 1];
        int qb2 = es[sB + eB + 2], qb3 = es[sB + eB + 3];
        unsigned ua0 = pbu[qa0 * 32 + l5], ua1 = pbu[qa1 * 32 + l5];
        unsigned ua2 = pbu[qa2 * 32 + l5], ua3 = pbu[qa3 * 32 + l5];
        unsigned ub0 = pbu[qb0 * 32 + l5], ub1 = pbu[qb1 * 32 + l5];
        unsigned ub2 = pbu[qb2 * 32 + l5], ub3 = pbu[qb3 * 32 + l5];
        a0 += bflo(ua0) + bflo(ua1) + bflo(ua2) + bflo(ua3);
        a1 += bfhi(ua0) + bfhi(ua1) + bfhi(ua2) + bfhi(ua3);
        b0 += bflo(ub0) + bflo(ub1) + bflo(ub2) + bflo(ub3);
        b1 += bfhi(ub0) + bfhi(ub1) + bfhi(ub2) + bfhi(ub3);
        eA += 4; eB += 4;
    }
    for (; eA + 4 <= dA; eA += 4) {
        int q0 = es[sA + eA + 0], q1 = es[sA + eA + 1];
        int q2 = es[sA + eA + 2], q3 = es[sA + eA + 3];
        unsigned u0 = pbu[q0 * 32 + l5], u1 = pbu[q1 * 32 + l5];
        unsigned u2 = pbu[q2 * 32 + l5], u3 = pbu[q3 * 32 + l5];
        a0 += bflo(u0) + bflo(u1) + bflo(u2) + bflo(u3);
        a1 += bfhi(u0) + bfhi(u1) + bfhi(u2) + bfhi(u3);
    }
    for (; eA < dA; ++eA) {
        unsigned u = pbu[es[sA + eA] * 32 + l5];
        a0 += bflo(u); a1 += bfhi(u);
    }
    for (; eB + 4 <= dB; eB += 4) {
        int q0 = es[sB + eB + 0], q1 = es[sB + eB + 1];
        int q2 = es[sB + eB + 2], q3 = es[sB + eB + 3];
        unsigned u0 = pbu[q0 * 32 + l5], u1 = pbu[q1 * 32 + l5];
        unsigned u2 = pbu[q2 * 32 + l5], u3 = pbu[q3 * 32 + l5];
        b0 += bflo(u0) + bflo(u1) + bflo(u2) + bflo(u3);
        b1 += bfhi(u0) + bfhi(u1) + bfhi(u2) + bfhi(u3);
    }
    for (; eB < dB; ++eB) {
        unsigned u = pbu[es[sB + eB] * 32 + l5];
        b0 += bflo(u); b1 += bfhi(u);
    }
    float invA = 1.0f / fmaxf((float)dA, 1.0f);
    float invB = 1.0f / fmaxf((float)dB, 1.0f);
    float2 oA = {pA.x + a0 * invA, pA.y + a1 * invA};
    float2 oB = {pB.x + b0 * invB, pB.y + b1 * invB};
    *(float2*)&out[(size_t)nA * 64 + 2 * l5] = oA;
    *(float2*)&out[(size_t)nB * 64 + 2 * l5] = oB;
}

// ---------------------------------------------------------------------------
// GEMM1 fused (MFMA): h = relu(mean@W1l + xr + b1) where xr = x@W1r was
// precomputed under agg1's shadow; pb = bf16(h@W2l); out = h@W2r + b2.
// ---------------------------------------------------------------------------
__global__ __launch_bounds__(256) void gemm1_kernel(const ushort* __restrict__ meanb,
                                                    const ushort* __restrict__ xrb,
                                                    const ushort* __restrict__ w1lp,
                                                    const float* __restrict__ b1,
                                                    const ushort* __restrict__ w2lp,
                                                    const ushort* __restrict__ w2rp,
                                                    const float* __restrict__ b2,
                                                    ushort* __restrict__ pb,
                                                    float* __restrict__ out) {
    __shared__ ushort As[64 * 136];
    int t = threadIdx.x;
    int node0 = blockIdx.x * 64;
    int w = t >> 6, l = t & 63;
    int lrow = w * 16 + (l & 15);
    int lkq = (l >> 4) * 8;
    int cq = l & 15, rq = (l >> 4) * 4;

    f32x4 acc[8];
#pragma unroll
    for (int i = 0; i < 8; ++i) acc[i] = (f32x4){0.f, 0.f, 0.f, 0.f};

    {
        const uint4* g = (const uint4*)(meanb + (size_t)node0 * 128);
#pragma unroll
        for (int i = 0; i < 4; ++i) {
            int chunk = t + 256 * i;
            *(uint4*)&As[(chunk >> 4) * 136 + (chunk & 15) * 8] = g[chunk];
        }
    }
    __syncthreads();
#pragma unroll
    for (int kt = 0; kt < 4; ++kt) {
        bf16x8 a = *(const bf16x8*)&As[lrow * 136 + kt * 32 + lkq];
        const bf16x8* bp = (const bf16x8*)w1lp + (kt * 8) * 64 + l;
#pragma unroll
        for (int nt = 0; nt < 8; ++nt)
            acc[nt] = __builtin_amdgcn_mfma_f32_16x16x32_bf16(a, bp[nt * 64], acc[nt], 0, 0, 0);
    }
    __syncthreads();

    // Stage xr tile (replaces the second MFMA pass).
    {
        const uint4* g = (const uint4*)(xrb + (size_t)node0 * 128);
#pragma unroll
        for (int i = 0; i < 4; ++i) {
            int chunk = t + 256 * i;
            *(uint4*)&As[(chunk >> 4) * 136 + (chunk & 15) * 8] = g[chunk];
        }
    }
    __syncthreads();

    // h = relu(acc + xr + b1), written back into the same As cells the thread
    // reads (bijective thread<->cell mapping, no cross-thread hazard).
#pragma unroll
    for (int nt = 0; nt < 8; ++nt) {
        int n = nt * 16 + cq;
        float bias = b1[n];
#pragma unroll
        for (int r = 0; r < 4; ++r) {
            int cell = (w * 16 + rq + r) * 136 + n;
            float hv = fmaxf(acc[nt][r] + bfu(As[cell]) + bias, 0.0f);
            As[cell] = f2bf(hv);
        }
    }
    __syncthreads();

    // Both second-layer products from the same h fragments.
    f32x4 acc2[4];  // h@W2l -> pb
    f32x4 acc3[4];  // h@W2r -> partial out
#pragma unroll
    for (int i = 0; i < 4; ++i) {
        acc2[i] = (f32x4){0.f, 0.f, 0.f, 0.f};
        acc3[i] = (f32x4){0.f, 0.f, 0.f, 0.f};
    }
#pragma unroll
    for (int kt = 0; kt < 4; ++kt) {
        bf16x8 a = *(const bf16x8*)&As[lrow * 136 + kt * 32 + lkq];
        const bf16x8* bpl = (const bf16x8*)w2lp + (kt * 4) * 64 + l;
        const bf16x8* bpr = (const bf16x8*)w2rp + (kt * 4) * 64 + l;
#pragma unroll
        for (int nt = 0; nt < 4; ++nt) {
            acc2[nt] = __builtin_amdgcn_mfma_f32_16x16x32_bf16(a, bpl[nt * 64], acc2[nt], 0, 0, 0);
            acc3[nt] = __builtin_amdgcn_mfma_f32_16x16x32_bf16(a, bpr[nt * 64], acc3[nt], 0, 0, 0);
        }
    }

    // Partial out = h@W2r + b2, straight from accumulators.
#pragma unroll
    for (int nt = 0; nt < 4; ++nt) {
        int n = nt * 16 + cq;
        float bias = b2[n];
#pragma unroll
        for (int r = 0; r < 4; ++r) {
            int row = node0 + w * 16 + rq + r;
            if (row < NN)
                out[(size_t)row * 64 + n] = acc3[nt][r] + bias;
        }
    }

    // pb = bf16(h@W2l) via LDS repack for vectorized store.
    __syncthreads();
#pragma unroll
    for (int nt = 0; nt < 4; ++nt)
#pragma unroll
        for (int r = 0; r < 4; ++r)
            As[(w * 16 + rq + r) * 136 + nt * 16 + cq] = f2bf(acc2[nt][r]);
    __syncthreads();
    {
        uint4* g = (uint4*)(pb + (size_t)node0 * 64);
#pragma unroll
        for (int i = 0; i < 2; ++i) {
            int chunk = t + 256 * i;
            if (node0 + (chunk >> 3) < NN)
                g[chunk] = *(const uint4*)&As[(chunk >> 3) * 136 + (chunk & 7) * 8];
        }
    }
}

extern "C" void kernel_launch(void* const* d_in, const int* in_sizes, int n_in,
                              void* d_out, int out_size, void* d_ws, size_t ws_size,
                              hipStream_t stream) {
    const float* x   = (const float*)d_in[0];
    const int*   ei  = (const int*)d_in[1];
    const float* W1l = (const float*)d_in[2];
    const float* W1r = (const float*)d_in[3];
    const float* b1  = (const float*)d_in[4];
    const float* W2l = (const float*)d_in[5];
    const float* W2r = (const float*)d_in[6];
    const float* b2  = (const float*)d_in[7];

    const int* src = ei;
    const int* dst = ei + NE;

    int*      ws_i   = (int*)d_ws;
    int*      cc     = ws_i + OFF_CC;
    int*      rstart = ws_i + OFF_RST;
    int*      rdeg   = ws_i + OFF_RDG;
    unsigned* stage  = (unsigned*)(ws_i + OFF_STAGE);
    ushort*   xb     = (ushort*)(ws_i + OFF_XB);
    unsigned* xf8    = (unsigned*)(ws_i + OFF_XF8);
    ushort*   pb     = (ushort*)(ws_i + OFF_XF8);   // aliases xf8 (disjoint lifetime)
    ushort*   meanb  = (ushort*)(ws_i + OFF_MEANB);
    ushort*   xrb    = (ushort*)(ws_i + OFF_XR);
    ushort*   w1lp   = (ushort*)(ws_i + OFF_W1LP);
    ushort*   w1rp   = (ushort*)(ws_i + OFF_W1RP);
    ushort*   w2lp   = (ushort*)(ws_i + OFF_W2LP);
    ushort*   w2rp   = (ushort*)(ws_i + OFF_W2RP);

    (void)hipMemsetAsync(cc, 0, 1024 * sizeof(int), stream);

    // Fused prep: cpart (1024-thread) + pack + cvt in one concurrent launch.
    prep_kernel<<<PREP_GRID, 1024, 0, stream>>>(
        x, xb, xf8, W1l, W1r, W2l, W2r, w1lp, w1rp, w2lp, w2rp, src, dst, cc, stage);
    sort_kernel<<<KB, 256, 0, stream>>>(stage, cc, rstart, rdeg);

    // Layer 1: gather + co-dispatched x@W1r GEMM under the gather's shadow.
    agg1f_kernel<<<A1_GRID, 256, 0, stream>>>(stage, rstart, rdeg, xf8, meanb,
                                              xb, w1rp, xrb);
    gemm1_kernel<<<(NN + 63) / 64, 256, 0, stream>>>(meanb, xrb, w1lp, b1,
                                                     w2lp, w2rp, b2, pb, (float*)d_out);

    // Layer 2: gather pb, mean, add into partial out.
    agg2g_kernel<<<NN / 16, 256, 0, stream>>>(stage, rstart, rdeg, pb, (float*)d_out);
}

// Round 7
// 245.341 us; speedup vs baseline: 1.4565x; 1.0752x over previous
//
#include <hip/hip_runtime.h>

#define NN 100000
#define NE 1600000
#define KB 782      // coarse buckets: ceil(100000/128)
#define BSH 7       // bucket = dst >> 7; 128 nodes per bucket
#define MAXB 4096   // fixed slots per bucket (mean 2046, max ~2250 — safe)
#define PBLK 400    // cpart blocks; NE/PBLK = 4000 edges per block

// Workspace layout in 4-byte units:
#define OFF_CC    0            // 1024: per-bucket edge counts
#define OFF_RST   1024         // 100096: per-node edge-range start (global slot index)
#define OFF_RDG   101120       // 100096: per-node degree
#define OFF_STAGE 201216       // KB*MAXB: packed (dstLow<<17)|src; node-sorted src after sort
#define OFF_XB    3404288      // x bf16 [100096,128]
#define OFF_XF8   9810432      // x fp8 [100096,128]; pb bf16 [100096,64] aliases (xf8 dead after agg1)
#define OFF_MEANB 13013504     // mean bf16 [100096,128]
#define OFF_W1LP  25825792     // packed weights bf16
#define OFF_W1RP  (25825792 + 8192)
#define OFF_W2LP  (25825792 + 16384)
#define OFF_W2RP  (25825792 + 20480)

typedef __bf16 bf16x8 __attribute__((ext_vector_type(8)));
typedef float f32x4 __attribute__((ext_vector_type(4)));
typedef float f32x2 __attribute__((ext_vector_type(2)));

static __device__ __forceinline__ ushort f2bf(float f) {
    unsigned u = __float_as_uint(f);
    return (ushort)((u + 0x7fffu + ((u >> 16) & 1u)) >> 16);
}
static __device__ __forceinline__ float bflo(unsigned u) { return __uint_as_float(u << 16); }
static __device__ __forceinline__ float bfhi(unsigned u) { return __uint_as_float(u & 0xffff0000u); }

// ---------------------------------------------------------------------------
// cpart (standalone, 1024 threads, 400 blocks): coarse partition into
// fixed-capacity bucket slots. Runs alone so sort can launch right after it
// (sort does NOT wait on cvt this way).
// ---------------------------------------------------------------------------
__global__ __launch_bounds__(1024) void cpart_kernel(const int* __restrict__ src,
                                                     const int* __restrict__ dst,
                                                     int* __restrict__ cc,
                                                     unsigned* __restrict__ stage) {
    __shared__ int hist[KB];
    __shared__ int cur[KB];
    int t = threadIdx.x;
    int e0 = blockIdx.x * (NE / PBLK);
    int e1 = e0 + (NE / PBLK);
    for (int i = t; i < KB; i += 1024) hist[i] = 0;
    __syncthreads();
    for (int e = e0 + t; e < e1; e += 1024)
        atomicAdd(&hist[dst[e] >> BSH], 1);
    __syncthreads();
    for (int i = t; i < KB; i += 1024) {
        int c = hist[i];
        cur[i] = c ? atomicAdd(&cc[i], c) : 0;
    }
    __syncthreads();
    for (int e = e0 + t; e < e1; e += 1024) {
        int d = dst[e];
        int bkt = d >> BSH;
        int p = atomicAdd(&cur[bkt], 1);
        if (p < MAXB)
            stage[bkt * MAXB + p] = ((unsigned)(d & 127) << 17) | (unsigned)src[e];
    }
}

// ---------------------------------------------------------------------------
// fused2 (1024 threads): sort [0,KB) + pack [KB,KB+6) + cvt [KB+6, KB+6+3125).
// sort depends only on cpart; cvt/pack are independent — co-dispatching them
// hides sort's ~10 us under cvt's streaming pass. sort blocks first (they
// gate nothing downstream earlier than cvt does, but finish first for agg1).
// ---------------------------------------------------------------------------
#define F2_SORT  KB
#define F2_PACKB 6      // 6 blocks x 4 virtual 256-thread sub-blocks = 24
#define F2_CVT   3125
#define F2_GRID  (F2_SORT + F2_PACKB + F2_CVT)

__global__ __launch_bounds__(1024) void fused2_kernel(
    unsigned* __restrict__ stage, const int* __restrict__ cc,
    int* __restrict__ rstart, int* __restrict__ rdeg,
    const float* __restrict__ x, ushort* __restrict__ xb, unsigned* __restrict__ xf8,
    const float* __restrict__ W1l, const float* __restrict__ W1r,
    const float* __restrict__ W2l, const float* __restrict__ W2r,
    ushort* __restrict__ w1lp, ushort* __restrict__ w1rp,
    ushort* __restrict__ w2lp, ushort* __restrict__ w2rp) {
    __shared__ unsigned ssrc[MAXB];
    __shared__ int sc[128];
    __shared__ int loff[129];
    __shared__ int lcur[128];
    int bid = blockIdx.x;
    int t = threadIdx.x;

    if (bid >= F2_SORT + F2_PACKB) {
        // ---- cvt: x fp32 -> xb bf16 + xf8 fp8 ----
        int i = (bid - F2_SORT - F2_PACKB) * 1024 + t;  // [0, 3.2M)
        float4 v = ((const float4*)x)[i];
        uint2 o;
        o.x = (unsigned)f2bf(v.x) | ((unsigned)f2bf(v.y) << 16);
        o.y = (unsigned)f2bf(v.z) | ((unsigned)f2bf(v.w) << 16);
        ((uint2*)xb)[i] = o;
        int p8 = __builtin_amdgcn_cvt_pk_fp8_f32(v.x, v.y, 0, false);
        p8 = __builtin_amdgcn_cvt_pk_fp8_f32(v.z, v.w, p8, true);
        xf8[i] = (unsigned)p8;
        return;
    }

    if (bid >= F2_SORT) {
        // ---- pack: weights fp32 -> bf16 MFMA B-frag layout ----
        int vb = (bid - F2_SORT) * 4 + (t >> 8);  // virtual 256-thread block [0,24)
        int vt = t & 255;
        const float* W;
        ushort* out;
        int N, frag0;
        if (vb < 8)       { W = W1l; out = w1lp; N = 128; frag0 = vb * 4; }
        else if (vb < 16) { W = W1r; out = w1rp; N = 128; frag0 = (vb - 8) * 4; }
        else if (vb < 20) { W = W2l; out = w2lp; N = 64;  frag0 = (vb - 16) * 4; }
        else              { W = W2r; out = w2rp; N = 64;  frag0 = (vb - 20) * 4; }
        int lane = vt & 63;
        int frag = frag0 + (vt >> 6);
        int NT = N >> 4;
        int ktile = frag / NT, ntile = frag - ktile * NT;
        int k = ktile * 32 + (lane >> 4) * 8;
        int n = ntile * 16 + (lane & 15);
        ushort tmp[8];
#pragma unroll
        for (int j = 0; j < 8; ++j) tmp[j] = f2bf(W[(k + j) * N + n]);
        uint4 o;
        o.x = (unsigned)tmp[0] | ((unsigned)tmp[1] << 16);
        o.y = (unsigned)tmp[2] | ((unsigned)tmp[3] << 16);
        o.z = (unsigned)tmp[4] | ((unsigned)tmp[5] << 16);
        o.w = (unsigned)tmp[6] | ((unsigned)tmp[7] << 16);
        *(uint4*)&out[(frag * 64 + lane) * 8] = o;
        return;
    }

    // ---- sort: per-bucket CSR build + in-place node-sorted writeback ----
    int b = bid;
    unsigned* st = stage + b * MAXB;
    int cnt = min(cc[b], MAXB);

    if (t < 128) lcur[t] = 0;
    __syncthreads();
    for (int i = t; i < cnt; i += 1024) atomicAdd(&lcur[st[i] >> 17], 1);
    __syncthreads();
    if (t < 128) sc[t] = lcur[t];
    __syncthreads();
    for (int off = 1; off < 128; off <<= 1) {
        int v = (t < 128 && t >= off) ? sc[t - off] : 0;
        __syncthreads();
        if (t < 128) sc[t] += v;
        __syncthreads();
    }
    if (t < 128) {
        int excl = (t == 0) ? 0 : sc[t - 1];
        loff[t] = excl;
        lcur[t] = excl;
    }
    if (t == 127) loff[128] = sc[127];
    __syncthreads();
    for (int i = t; i < cnt; i += 1024) {
        unsigned v = st[i];
        int p = atomicAdd(&lcur[v >> 17], 1);
        ssrc[p] = v & 0x1FFFFu;
    }
    __syncthreads();
    for (int i = t; i < cnt; i += 1024) st[i] = ssrc[i];
    int node0 = b << BSH;
    if (t < 128 && node0 + t < NN) {
        rstart[node0 + t] = b * MAXB + loff[t];
        rdeg[node0 + t] = loff[t + 1] - loff[t];
    }
}

// ---------------------------------------------------------------------------
// Layer-1 gather (fp8): 16 lanes/node, 2-node interleave (round-3 structure,
// verified best) + LDS-staged edge indices: each block's 32 nodes own a
// contiguous es range (32 | 128 bucket nodes); stage it via nontemporal loads
// (es must not evict the hot gather table from L2), then the inner loop's
// index reads are LDS — all vmcnt slots go to gathers. Grid 3125 x 256.
// ---------------------------------------------------------------------------
static __device__ __forceinline__ void accum8(float* a, uint2 u) {
    f32x2 p0 = __builtin_amdgcn_cvt_pk_f32_fp8(u.x, false);
    f32x2 p1 = __builtin_amdgcn_cvt_pk_f32_fp8(u.x, true);
    f32x2 p2 = __builtin_amdgcn_cvt_pk_f32_fp8(u.y, false);
    f32x2 p3 = __builtin_amdgcn_cvt_pk_f32_fp8(u.y, true);
    a[0] += p0.x; a[1] += p0.y; a[2] += p1.x; a[3] += p1.y;
    a[4] += p2.x; a[5] += p2.y; a[6] += p3.x; a[7] += p3.y;
}

static __device__ __forceinline__ void writeRow8(ushort* __restrict__ meanb, int node,
                                                 int l4, const float* a, int deg) {
    float inv = 1.0f / fmaxf((float)deg, 1.0f);
    uint4 o;
    o.x = (unsigned)f2bf(a[0] * inv) | ((unsigned)f2bf(a[1] * inv) << 16);
    o.y = (unsigned)f2bf(a[2] * inv) | ((unsigned)f2bf(a[3] * inv) << 16);
    o.z = (unsigned)f2bf(a[4] * inv) | ((unsigned)f2bf(a[5] * inv) << 16);
    o.w = (unsigned)f2bf(a[6] * inv) | ((unsigned)f2bf(a[7] * inv) << 16);
    *(uint4*)&meanb[node * 128 + 8 * l4] = o;
}

__global__ __launch_bounds__(256) void agg1g_kernel(const unsigned* __restrict__ es,
                                                    const int* __restrict__ rstart,
                                                    const int* __restrict__ rdeg,
                                                    const unsigned* __restrict__ xf8,
                                                    ushort* __restrict__ meanb) {
    __shared__ unsigned eidx[MAXB];
    int t = threadIdx.x;
    int node0 = blockIdx.x * 32;
    int eBase = rstart[node0];
    int last = node0 + 31;
    int cnt = rstart[last] + rdeg[last] - eBase;
    for (int i = t; i < cnt; i += 256)
        eidx[i] = __builtin_nontemporal_load(&es[eBase + i]);
    __syncthreads();

    int l4 = t & 15;
    int nA = node0 + (t >> 4) * 2;
    int nB = nA + 1;
    int sA = rstart[nA] - eBase, dA = rdeg[nA];
    int sB = rstart[nB] - eBase, dB = rdeg[nB];
    const uint2* xv = (const uint2*)xf8;  // row = 16 uint2 (128 fp8)
    float aA[8] = {0.f, 0.f, 0.f, 0.f, 0.f, 0.f, 0.f, 0.f};
    float aB[8] = {0.f, 0.f, 0.f, 0.f, 0.f, 0.f, 0.f, 0.f};
    int eA = 0, eB = 0;
    while (eA + 4 <= dA && eB + 4 <= dB) {
        int qa0 = eidx[sA + eA + 0], qa1 = eidx[sA + eA + 1];
        int qa2 = eidx[sA + eA + 2], qa3 = eidx[sA + eA + 3];
        int qb0 = eidx[sB + eB + 0], qb1 = eidx[sB + eB + 1];
        int qb2 = eidx[sB + eB + 2], qb3 = eidx[sB + eB + 3];
        uint2 ua0 = xv[qa0 * 16 + l4], ua1 = xv[qa1 * 16 + l4];
        uint2 ua2 = xv[qa2 * 16 + l4], ua3 = xv[qa3 * 16 + l4];
        uint2 ub0 = xv[qb0 * 16 + l4], ub1 = xv[qb1 * 16 + l4];
        uint2 ub2 = xv[qb2 * 16 + l4], ub3 = xv[qb3 * 16 + l4];
        accum8(aA, ua0); accum8(aA, ua1); accum8(aA, ua2); accum8(aA, ua3);
        accum8(aB, ub0); accum8(aB, ub1); accum8(aB, ub2); accum8(aB, ub3);
        eA += 4; eB += 4;
    }
    for (; eA + 4 <= dA; eA += 4) {
        int q0 = eidx[sA + eA + 0], q1 = eidx[sA + eA + 1];
        int q2 = eidx[sA + eA + 2], q3 = eidx[sA + eA + 3];
        uint2 u0 = xv[q0 * 16 + l4], u1 = xv[q1 * 16 + l4];
        uint2 u2 = xv[q2 * 16 + l4], u3 = xv[q3 * 16 + l4];
        accum8(aA, u0); accum8(aA, u1); accum8(aA, u2); accum8(aA, u3);
    }
    for (; eA < dA; ++eA) accum8(aA, xv[eidx[sA + eA] * 16 + l4]);
    for (; eB + 4 <= dB; eB += 4) {
        int q0 = eidx[sB + eB + 0], q1 = eidx[sB + eB + 1];
        int q2 = eidx[sB + eB + 2], q3 = eidx[sB + eB + 3];
        uint2 u0 = xv[q0 * 16 + l4], u1 = xv[q1 * 16 + l4];
        uint2 u2 = xv[q2 * 16 + l4], u3 = xv[q3 * 16 + l4];
        accum8(aB, u0); accum8(aB, u1); accum8(aB, u2); accum8(aB, u3);
    }
    for (; eB < dB; ++eB) accum8(aB, xv[eidx[sB + eB] * 16 + l4]);

    writeRow8(meanb, nA, l4, aA, dA);
    writeRow8(meanb, nB, l4, aB, dB);
}

// ---------------------------------------------------------------------------
// Layer-2 gather + final combine (round-3 structure + LDS edge staging):
// gathers pb (bf16), means, out[node] = partial_out + mean. 32 lanes/node,
// 2-node interleave, 16 nodes/block (16 | 128). Grid 6250 x 256.
// ---------------------------------------------------------------------------
__global__ __launch_bounds__(256) void agg2g_kernel(const unsigned* __restrict__ es,
                                                    const int* __restrict__ rstart,
                                                    const int* __restrict__ rdeg,
                                                    const ushort* __restrict__ pb,
                                                    float* __restrict__ out) {
    __shared__ unsigned eidx[MAXB];
    int t = threadIdx.x;
    int node0 = blockIdx.x * 16;
    int eBase = rstart[node0];
    int last = node0 + 15;
    int cnt = rstart[last] + rdeg[last] - eBase;
    for (int i = t; i < cnt; i += 256)
        eidx[i] = __builtin_nontemporal_load(&es[eBase + i]);
    __syncthreads();

    int l5 = t & 31;
    int nA = node0 + (t >> 5) * 2;
    int nB = nA + 1;
    int sA = rstart[nA] - eBase, dA = rdeg[nA];
    int sB = rstart[nB] - eBase, dB = rdeg[nB];
    float2 pA = *(const float2*)&out[(size_t)nA * 64 + 2 * l5];
    float2 pB = *(const float2*)&out[(size_t)nB * 64 + 2 * l5];
    const unsigned* pbu = (const unsigned*)pb;  // row = 32 uint (64 bf16)
    float a0 = 0.f, a1 = 0.f, b0 = 0.f, b1 = 0.f;
    int eA = 0, eB = 0;
    while (eA + 4 <= dA && eB + 4 <= dB) {
        int qa0 = eidx[sA + eA + 0], qa1 = eidx[sA + eA + 1];
        int qa2 = eidx[sA + eA + 2], qa3 = eidx[sA + eA + 3];
        int qb0 = eidx[sB + eB + 0], qb1 = eidx[sB + eB + 1];
        int qb2 = eidx[sB + eB + 2], qb3 = eidx[sB + eB + 3];
        unsigned ua0 = pbu[qa0 * 32 + l5], ua1 = pbu[qa1 * 32 + l5];
        unsigned ua2 = pbu[qa2 * 32 + l5], ua3 = pbu[qa3 * 32 + l5];
        unsigned ub0 = pbu[qb0 * 32 + l5], ub1 = pbu[qb1 * 32 + l5];
        unsigned ub2 = pbu[qb2 * 32 + l5], ub3 = pbu[qb3 * 32 + l5];
        a0 += bflo(ua0) + bflo(ua1) + bflo(ua2) + bflo(ua3);
        a1 += bfhi(ua0) + bfhi(ua1) + bfhi(ua2) + bfhi(ua3);
        b0 += bflo(ub0) + bflo(ub1) + bflo(ub2) + bflo(ub3);
        b1 += bfhi(ub0) + bfhi(ub1) + bfhi(ub2) + bfhi(ub3);
        eA += 4; eB += 4;
    }
    for (; eA + 4 <= dA; eA += 4) {
        int q0 = eidx[sA + eA + 0], q1 = eidx[sA + eA + 1];
        int q2 = eidx[sA + eA + 2], q3 = eidx[sA + eA + 3];
        unsigned u0 = pbu[q0 * 32 + l5], u1 = pbu[q1 * 32 + l5];
        unsigned u2 = pbu[q2 * 32 + l5], u3 = pbu[q3 * 32 + l5];
        a0 += bflo(u0) + bflo(u1) + bflo(u2) + bflo(u3);
        a1 += bfhi(u0) + bfhi(u1) + bfhi(u2) + bfhi(u3);
    }
    for (; eA < dA; ++eA) {
        unsigned u = pbu[eidx[sA + eA] * 32 + l5];
        a0 += bflo(u); a1 += bfhi(u);
    }
    for (; eB + 4 <= dB; eB += 4) {
        int q0 = eidx[sB + eB + 0], q1 = eidx[sB + eB + 1];
        int q2 = eidx[sB + eB + 2], q3 = eidx[sB + eB + 3];
        unsigned u0 = pbu[q0 * 32 + l5], u1 = pbu[q1 * 32 + l5];
        unsigned u2 = pbu[q2 * 32 + l5], u3 = pbu[q3 * 32 + l5];
        b0 += bflo(u0) + bflo(u1) + bflo(u2) + bflo(u3);
        b1 += bfhi(u0) + bfhi(u1) + bfhi(u2) + bfhi(u3);
    }
    for (; eB < dB; ++eB) {
        unsigned u = pbu[eidx[sB + eB] * 32 + l5];
        b0 += bflo(u); b1 += bfhi(u);
    }
    float invA = 1.0f / fmaxf((float)dA, 1.0f);
    float invB = 1.0f / fmaxf((float)dB, 1.0f);
    float2 oA = {pA.x + a0 * invA, pA.y + a1 * invA};
    float2 oB = {pB.x + b0 * invB, pB.y + b1 * invB};
    *(float2*)&out[(size_t)nA * 64 + 2 * l5] = oA;
    *(float2*)&out[(size_t)nB * 64 + 2 * l5] = oB;
}

// ---------------------------------------------------------------------------
// GEMM1 fused (MFMA, round-3 verified): h = relu(mean@W1l + x@W1r + b1);
//   pb  = bf16(h@W2l)   (for the layer-2 gather)
//   out = h@W2r + b2    (partial final output; agg2g adds the mean)
// ---------------------------------------------------------------------------
__global__ __launch_bounds__(256) void gemm1_kernel(const ushort* __restrict__ meanb,
                                                    const ushort* __restrict__ xb,
                                                    const ushort* __restrict__ w1lp,
                                                    const ushort* __restrict__ w1rp,
                                                    const float* __restrict__ b1,
                                                    const ushort* __restrict__ w2lp,
                                                    const ushort* __restrict__ w2rp,
                                                    const float* __restrict__ b2,
                                                    ushort* __restrict__ pb,
                                                    float* __restrict__ out) {
    __shared__ ushort As[64 * 136];
    int t = threadIdx.x;
    int node0 = blockIdx.x * 64;
    int w = t >> 6, l = t & 63;
    int lrow = w * 16 + (l & 15);
    int lkq = (l >> 4) * 8;
    int cq = l & 15, rq = (l >> 4) * 4;

    f32x4 acc[8];
#pragma unroll
    for (int i = 0; i < 8; ++i) acc[i] = (f32x4){0.f, 0.f, 0.f, 0.f};

    {
        const uint4* g = (const uint4*)(meanb + (size_t)node0 * 128);
#pragma unroll
        for (int i = 0; i < 4; ++i) {
            int chunk = t + 256 * i;
            *(uint4*)&As[(chunk >> 4) * 136 + (chunk & 15) * 8] = g[chunk];
        }
    }
    __syncthreads();
#pragma unroll
    for (int kt = 0; kt < 4; ++kt) {
        bf16x8 a = *(const bf16x8*)&As[lrow * 136 + kt * 32 + lkq];
        const bf16x8* bp = (const bf16x8*)w1lp + (kt * 8) * 64 + l;
#pragma unroll
        for (int nt = 0; nt < 8; ++nt)
            acc[nt] = __builtin_amdgcn_mfma_f32_16x16x32_bf16(a, bp[nt * 64], acc[nt], 0, 0, 0);
    }
    __syncthreads();

    {
        const uint4* g = (const uint4*)(xb + (size_t)node0 * 128);
#pragma unroll
        for (int i = 0; i < 4; ++i) {
            int chunk = t + 256 * i;
            *(uint4*)&As[(chunk >> 4) * 136 + (chunk & 15) * 8] = g[chunk];
        }
    }
    __syncthreads();
#pragma unroll
    for (int kt = 0; kt < 4; ++kt) {
        bf16x8 a = *(const bf16x8*)&As[lrow * 136 + kt * 32 + lkq];
        const bf16x8* bp = (const bf16x8*)w1rp + (kt * 8) * 64 + l;
#pragma unroll
        for (int nt = 0; nt < 8; ++nt)
            acc[nt] = __builtin_amdgcn_mfma_f32_16x16x32_bf16(a, bp[nt * 64], acc[nt], 0, 0, 0);
    }
    __syncthreads();

    // h (relu + bias) back into As as bf16.
#pragma unroll
    for (int nt = 0; nt < 8; ++nt) {
        int n = nt * 16 + cq;
        float bias = b1[n];
#pragma unroll
        for (int r = 0; r < 4; ++r) {
            float hv = fmaxf(acc[nt][r] + bias, 0.0f);
            As[(w * 16 + rq + r) * 136 + n] = f2bf(hv);
        }
    }
    __syncthreads();

    // Both second-layer products from the same h fragments.
    f32x4 acc2[4];  // h@W2l -> pb
    f32x4 acc3[4];  // h@W2r -> partial out
#pragma unroll
    for (int i = 0; i < 4; ++i) {
        acc2[i] = (f32x4){0.f, 0.f, 0.f, 0.f};
        acc3[i] = (f32x4){0.f, 0.f, 0.f, 0.f};
    }
#pragma unroll
    for (int kt = 0; kt < 4; ++kt) {
        bf16x8 a = *(const bf16x8*)&As[lrow * 136 + kt * 32 + lkq];
        const bf16x8* bpl = (const bf16x8*)w2lp + (kt * 4) * 64 + l;
        const bf16x8* bpr = (const bf16x8*)w2rp + (kt * 4) * 64 + l;
#pragma unroll
        for (int nt = 0; nt < 4; ++nt) {
            acc2[nt] = __builtin_amdgcn_mfma_f32_16x16x32_bf16(a, bpl[nt * 64], acc2[nt], 0, 0, 0);
            acc3[nt] = __builtin_amdgcn_mfma_f32_16x16x32_bf16(a, bpr[nt * 64], acc3[nt], 0, 0, 0);
        }
    }

    // Partial out = h@W2r + b2, straight from accumulators.
#pragma unroll
    for (int nt = 0; nt < 4; ++nt) {
        int n = nt * 16 + cq;
        float bias = b2[n];
#pragma unroll
        for (int r = 0; r < 4; ++r) {
            int row = node0 + w * 16 + rq + r;
            if (row < NN)
                out[(size_t)row * 64 + n] = acc3[nt][r] + bias;
        }
    }

    // pb = bf16(h@W2l) via LDS repack for vectorized store.
    __syncthreads();
#pragma unroll
    for (int nt = 0; nt < 4; ++nt)
#pragma unroll
        for (int r = 0; r < 4; ++r)
            As[(w * 16 + rq + r) * 136 + nt * 16 + cq] = f2bf(acc2[nt][r]);
    __syncthreads();
    {
        uint4* g = (uint4*)(pb + (size_t)node0 * 64);
#pragma unroll
        for (int i = 0; i < 2; ++i) {
            int chunk = t + 256 * i;
            if (node0 + (chunk >> 3) < NN)
                g[chunk] = *(const uint4*)&As[(chunk >> 3) * 136 + (chunk & 7) * 8];
        }
    }
}

extern "C" void kernel_launch(void* const* d_in, const int* in_sizes, int n_in,
                              void* d_out, int out_size, void* d_ws, size_t ws_size,
                              hipStream_t stream) {
    const float* x   = (const float*)d_in[0];
    const int*   ei  = (const int*)d_in[1];
    const float* W1l = (const float*)d_in[2];
    const float* W1r = (const float*)d_in[3];
    const float* b1  = (const float*)d_in[4];
    const float* W2l = (const float*)d_in[5];
    const float* W2r = (const float*)d_in[6];
    const float* b2  = (const float*)d_in[7];

    const int* src = ei;
    const int* dst = ei + NE;

    int*      ws_i   = (int*)d_ws;
    int*      cc     = ws_i + OFF_CC;
    int*      rstart = ws_i + OFF_RST;
    int*      rdeg   = ws_i + OFF_RDG;
    unsigned* stage  = (unsigned*)(ws_i + OFF_STAGE);
    ushort*   xb     = (ushort*)(ws_i + OFF_XB);
    unsigned* xf8    = (unsigned*)(ws_i + OFF_XF8);
    ushort*   pb     = (ushort*)(ws_i + OFF_XF8);   // aliases xf8 (disjoint lifetime)
    ushort*   meanb  = (ushort*)(ws_i + OFF_MEANB);
    ushort*   w1lp   = (ushort*)(ws_i + OFF_W1LP);
    ushort*   w1rp   = (ushort*)(ws_i + OFF_W1RP);
    ushort*   w2lp   = (ushort*)(ws_i + OFF_W2LP);
    ushort*   w2rp   = (ushort*)(ws_i + OFF_W2RP);

    (void)hipMemsetAsync(cc, 0, 1024 * sizeof(int), stream);

    // cpart alone (sort's only dependency), then sort co-dispatched with
    // pack+cvt so sort's latency hides under cvt's streaming pass.
    cpart_kernel<<<PBLK, 1024, 0, stream>>>(src, dst, cc, stage);
    fused2_kernel<<<F2_GRID, 1024, 0, stream>>>(
        stage, cc, rstart, rdeg, x, xb, xf8,
        W1l, W1r, W2l, W2r, w1lp, w1rp, w2lp, w2rp);

    // Layer 1: gather (LDS-staged indices) + fused GEMM (both W2 products).
    agg1g_kernel<<<NN / 32, 256, 0, stream>>>(stage, rstart, rdeg, xf8, meanb);
    gemm1_kernel<<<(NN + 63) / 64, 256, 0, stream>>>(meanb, xb, w1lp, w1rp, b1,
                                                     w2lp, w2rp, b2, pb, (float*)d_out);

    // Layer 2: gather pb, mean, add into partial out.
    agg2g_kernel<<<NN / 16, 256, 0, stream>>>(stage, rstart, rdeg, pb, (float*)d_out);
}

// Round 9
// 234.952 us; speedup vs baseline: 1.5209x; 1.0442x over previous
//
#include <hip/hip_runtime.h>

#define NN 100000
#define NE 1600000
#define KB 782      // coarse buckets: ceil(100000/128)
#define BSH 7       // bucket = dst >> 7; 128 nodes per bucket
#define MAXB 4096   // fixed slots per bucket (mean 2046, max ~2250 — safe)
#define PBLK 400    // cpart blocks; NE/PBLK = 4000 edges per block

// Workspace layout in 4-byte units:
#define OFF_CC    0            // 1024: per-bucket edge counts
#define OFF_RST   1024         // 100096: per-node edge-range start (global slot index)
#define OFF_RDG   101120       // 100096: per-node degree
#define OFF_STAGE 201216       // KB*MAXB: packed (dstLow<<17)|src; node-sorted src after sort
#define OFF_XB    3404288      // x bf16 [100096,128]
#define OFF_XF8   9810432      // x fp8 [100096,128]; pb bf16 [100096,64] aliases (xf8 dead after agg1)
#define OFF_MEANB 13013504     // mean bf16 [100096,128]
#define OFF_W1LP  25825792     // packed weights bf16
#define OFF_W1RP  (25825792 + 8192)
#define OFF_W2LP  (25825792 + 16384)
#define OFF_W2RP  (25825792 + 20480)

typedef __bf16 bf16x8 __attribute__((ext_vector_type(8)));
typedef float f32x4 __attribute__((ext_vector_type(4)));
typedef float f32x2 __attribute__((ext_vector_type(2)));

static __device__ __forceinline__ ushort f2bf(float f) {
    unsigned u = __float_as_uint(f);
    return (ushort)((u + 0x7fffu + ((u >> 16) & 1u)) >> 16);
}
static __device__ __forceinline__ float bflo(unsigned u) { return __uint_as_float(u << 16); }
static __device__ __forceinline__ float bfhi(unsigned u) { return __uint_as_float(u & 0xffff0000u); }

// ---------------------------------------------------------------------------
// cpart (standalone, 1024 threads, 400 blocks): coarse partition into
// fixed-capacity bucket slots.
// ---------------------------------------------------------------------------
__global__ __launch_bounds__(1024) void cpart_kernel(const int* __restrict__ src,
                                                     const int* __restrict__ dst,
                                                     int* __restrict__ cc,
                                                     unsigned* __restrict__ stage) {
    __shared__ int hist[KB];
    __shared__ int cur[KB];
    int t = threadIdx.x;
    int e0 = blockIdx.x * (NE / PBLK);
    int e1 = e0 + (NE / PBLK);
    for (int i = t; i < KB; i += 1024) hist[i] = 0;
    __syncthreads();
    for (int e = e0 + t; e < e1; e += 1024)
        atomicAdd(&hist[dst[e] >> BSH], 1);
    __syncthreads();
    for (int i = t; i < KB; i += 1024) {
        int c = hist[i];
        cur[i] = c ? atomicAdd(&cc[i], c) : 0;
    }
    __syncthreads();
    for (int e = e0 + t; e < e1; e += 1024) {
        int d = dst[e];
        int bkt = d >> BSH;
        int p = atomicAdd(&cur[bkt], 1);
        if (p < MAXB)
            stage[bkt * MAXB + p] = ((unsigned)(d & 127) << 17) | (unsigned)src[e];
    }
}

// ---------------------------------------------------------------------------
// fused2 (1024 threads): sort [0,KB) + pack [KB,KB+6) + cvt rest.
// ---------------------------------------------------------------------------
#define F2_SORT  KB
#define F2_PACKB 6      // 6 blocks x 4 virtual 256-thread sub-blocks = 24
#define F2_CVT   3125
#define F2_GRID  (F2_SORT + F2_PACKB + F2_CVT)

__global__ __launch_bounds__(1024) void fused2_kernel(
    unsigned* __restrict__ stage, const int* __restrict__ cc,
    int* __restrict__ rstart, int* __restrict__ rdeg,
    const float* __restrict__ x, ushort* __restrict__ xb, unsigned* __restrict__ xf8,
    const float* __restrict__ W1l, const float* __restrict__ W1r,
    const float* __restrict__ W2l, const float* __restrict__ W2r,
    ushort* __restrict__ w1lp, ushort* __restrict__ w1rp,
    ushort* __restrict__ w2lp, ushort* __restrict__ w2rp) {
    __shared__ unsigned ssrc[MAXB];
    __shared__ int sc[128];
    __shared__ int loff[129];
    __shared__ int lcur[128];
    int bid = blockIdx.x;
    int t = threadIdx.x;

    if (bid >= F2_SORT + F2_PACKB) {
        // ---- cvt: x fp32 -> xb bf16 + xf8 fp8 ----
        int i = (bid - F2_SORT - F2_PACKB) * 1024 + t;  // [0, 3.2M)
        float4 v = ((const float4*)x)[i];
        uint2 o;
        o.x = (unsigned)f2bf(v.x) | ((unsigned)f2bf(v.y) << 16);
        o.y = (unsigned)f2bf(v.z) | ((unsigned)f2bf(v.w) << 16);
        ((uint2*)xb)[i] = o;
        int p8 = __builtin_amdgcn_cvt_pk_fp8_f32(v.x, v.y, 0, false);
        p8 = __builtin_amdgcn_cvt_pk_fp8_f32(v.z, v.w, p8, true);
        xf8[i] = (unsigned)p8;
        return;
    }

    if (bid >= F2_SORT) {
        // ---- pack: weights fp32 -> bf16 MFMA B-frag layout ----
        int vb = (bid - F2_SORT) * 4 + (t >> 8);  // virtual 256-thread block [0,24)
        int vt = t & 255;
        const float* W;
        ushort* out;
        int N, frag0;
        if (vb < 8)       { W = W1l; out = w1lp; N = 128; frag0 = vb * 4; }
        else if (vb < 16) { W = W1r; out = w1rp; N = 128; frag0 = (vb - 8) * 4; }
        else if (vb < 20) { W = W2l; out = w2lp; N = 64;  frag0 = (vb - 16) * 4; }
        else              { W = W2r; out = w2rp; N = 64;  frag0 = (vb - 20) * 4; }
        int lane = vt & 63;
        int frag = frag0 + (vt >> 6);
        int NT = N >> 4;
        int ktile = frag / NT, ntile = frag - ktile * NT;
        int k = ktile * 32 + (lane >> 4) * 8;
        int n = ntile * 16 + (lane & 15);
        ushort tmp[8];
#pragma unroll
        for (int j = 0; j < 8; ++j) tmp[j] = f2bf(W[(k + j) * N + n]);
        uint4 o;
        o.x = (unsigned)tmp[0] | ((unsigned)tmp[1] << 16);
        o.y = (unsigned)tmp[2] | ((unsigned)tmp[3] << 16);
        o.z = (unsigned)tmp[4] | ((unsigned)tmp[5] << 16);
        o.w = (unsigned)tmp[6] | ((unsigned)tmp[7] << 16);
        *(uint4*)&out[(frag * 64 + lane) * 8] = o;
        return;
    }

    // ---- sort: per-bucket CSR build + in-place node-sorted writeback ----
    int b = bid;
    unsigned* st = stage + b * MAXB;
    int cnt = min(cc[b], MAXB);

    if (t < 128) lcur[t] = 0;
    __syncthreads();
    for (int i = t; i < cnt; i += 1024) atomicAdd(&lcur[st[i] >> 17], 1);
    __syncthreads();
    if (t < 128) sc[t] = lcur[t];
    __syncthreads();
    for (int off = 1; off < 128; off <<= 1) {
        int v = (t < 128 && t >= off) ? sc[t - off] : 0;
        __syncthreads();
        if (t < 128) sc[t] += v;
        __syncthreads();
    }
    if (t < 128) {
        int excl = (t == 0) ? 0 : sc[t - 1];
        loff[t] = excl;
        lcur[t] = excl;
    }
    if (t == 127) loff[128] = sc[127];
    __syncthreads();
    for (int i = t; i < cnt; i += 1024) {
        unsigned v = st[i];
        int p = atomicAdd(&lcur[v >> 17], 1);
        ssrc[p] = v & 0x1FFFFu;
    }
    __syncthreads();
    for (int i = t; i < cnt; i += 1024) st[i] = ssrc[i];
    int node0 = b << BSH;
    if (t < 128 && node0 + t < NN) {
        rstart[node0 + t] = b * MAXB + loff[t];
        rdeg[node0 + t] = loff[t + 1] - loff[t];
    }
}

// ---------------------------------------------------------------------------
// Layer-1 gather (fp8): 16 lanes/node, 2-node interleave, LDS-staged edge
// indices (nontemporal). Grid 3125 x 256.
// ---------------------------------------------------------------------------
static __device__ __forceinline__ void accum8(float* a, uint2 u) {
    f32x2 p0 = __builtin_amdgcn_cvt_pk_f32_fp8(u.x, false);
    f32x2 p1 = __builtin_amdgcn_cvt_pk_f32_fp8(u.x, true);
    f32x2 p2 = __builtin_amdgcn_cvt_pk_f32_fp8(u.y, false);
    f32x2 p3 = __builtin_amdgcn_cvt_pk_f32_fp8(u.y, true);
    a[0] += p0.x; a[1] += p0.y; a[2] += p1.x; a[3] += p1.y;
    a[4] += p2.x; a[5] += p2.y; a[6] += p3.x; a[7] += p3.y;
}

static __device__ __forceinline__ void writeRow8(ushort* __restrict__ meanb, int node,
                                                 int l4, const float* a, int deg) {
    float inv = 1.0f / fmaxf((float)deg, 1.0f);
    uint4 o;
    o.x = (unsigned)f2bf(a[0] * inv) | ((unsigned)f2bf(a[1] * inv) << 16);
    o.y = (unsigned)f2bf(a[2] * inv) | ((unsigned)f2bf(a[3] * inv) << 16);
    o.z = (unsigned)f2bf(a[4] * inv) | ((unsigned)f2bf(a[5] * inv) << 16);
    o.w = (unsigned)f2bf(a[6] * inv) | ((unsigned)f2bf(a[7] * inv) << 16);
    *(uint4*)&meanb[node * 128 + 8 * l4] = o;
}

__global__ __launch_bounds__(256) void agg1g_kernel(const unsigned* __restrict__ es,
                                                    const int* __restrict__ rstart,
                                                    const int* __restrict__ rdeg,
                                                    const unsigned* __restrict__ xf8,
                                                    ushort* __restrict__ meanb) {
    __shared__ unsigned eidx[MAXB];
    int t = threadIdx.x;
    int node0 = blockIdx.x * 32;
    int eBase = rstart[node0];
    int last = node0 + 31;
    int cnt = rstart[last] + rdeg[last] - eBase;
    for (int i = t; i < cnt; i += 256)
        eidx[i] = __builtin_nontemporal_load(&es[eBase + i]);
    __syncthreads();

    int l4 = t & 15;
    int nA = node0 + (t >> 4) * 2;
    int nB = nA + 1;
    int sA = rstart[nA] - eBase, dA = rdeg[nA];
    int sB = rstart[nB] - eBase, dB = rdeg[nB];
    const uint2* xv = (const uint2*)xf8;  // row = 16 uint2 (128 fp8)
    float aA[8] = {0.f, 0.f, 0.f, 0.f, 0.f, 0.f, 0.f, 0.f};
    float aB[8] = {0.f, 0.f, 0.f, 0.f, 0.f, 0.f, 0.f, 0.f};
    int eA = 0, eB = 0;
    while (eA + 4 <= dA && eB + 4 <= dB) {
        int qa0 = eidx[sA + eA + 0], qa1 = eidx[sA + eA + 1];
        int qa2 = eidx[sA + eA + 2], qa3 = eidx[sA + eA + 3];
        int qb0 = eidx[sB + eB + 0], qb1 = eidx[sB + eB + 1];
        int qb2 = eidx[sB + eB + 2], qb3 = eidx[sB + eB + 3];
        uint2 ua0 = xv[qa0 * 16 + l4], ua1 = xv[qa1 * 16 + l4];
        uint2 ua2 = xv[qa2 * 16 + l4], ua3 = xv[qa3 * 16 + l4];
        uint2 ub0 = xv[qb0 * 16 + l4], ub1 = xv[qb1 * 16 + l4];
        uint2 ub2 = xv[qb2 * 16 + l4], ub3 = xv[qb3 * 16 + l4];
        accum8(aA, ua0); accum8(aA, ua1); accum8(aA, ua2); accum8(aA, ua3);
        accum8(aB, ub0); accum8(aB, ub1); accum8(aB, ub2); accum8(aB, ub3);
        eA += 4; eB += 4;
    }
    for (; eA + 4 <= dA; eA += 4) {
        int q0 = eidx[sA + eA + 0], q1 = eidx[sA + eA + 1];
        int q2 = eidx[sA + eA + 2], q3 = eidx[sA + eA + 3];
        uint2 u0 = xv[q0 * 16 + l4], u1 = xv[q1 * 16 + l4];
        uint2 u2 = xv[q2 * 16 + l4], u3 = xv[q3 * 16 + l4];
        accum8(aA, u0); accum8(aA, u1); accum8(aA, u2); accum8(aA, u3);
    }
    for (; eA < dA; ++eA) accum8(aA, xv[eidx[sA + eA] * 16 + l4]);
    for (; eB + 4 <= dB; eB += 4) {
        int q0 = eidx[sB + eB + 0], q1 = eidx[sB + eB + 1];
        int q2 = eidx[sB + eB + 2], q3 = eidx[sB + eB + 3];
        uint2 u0 = xv[q0 * 16 + l4], u1 = xv[q1 * 16 + l4];
        uint2 u2 = xv[q2 * 16 + l4], u3 = xv[q3 * 16 + l4];
        accum8(aB, u0); accum8(aB, u1); accum8(aB, u2); accum8(aB, u3);
    }
    for (; eB < dB; ++eB) accum8(aB, xv[eidx[sB + eB] * 16 + l4]);

    writeRow8(meanb, nA, l4, aA, dA);
    writeRow8(meanb, nB, l4, aB, dB);
}

// ---------------------------------------------------------------------------
// Layer-2 gather + final combine: gathers pb (bf16), means, out = partial+mean.
// 32 lanes/node, 2-node interleave, LDS-staged edge indices. Grid 6250 x 256.
// ---------------------------------------------------------------------------
__global__ __launch_bounds__(256) void agg2g_kernel(const unsigned* __restrict__ es,
                                                    const int* __restrict__ rstart,
                                                    const int* __restrict__ rdeg,
                                                    const ushort* __restrict__ pb,
                                                    float* __restrict__ out) {
    __shared__ unsigned eidx[MAXB];
    int t = threadIdx.x;
    int node0 = blockIdx.x * 16;
    int eBase = rstart[node0];
    int last = node0 + 15;
    int cnt = rstart[last] + rdeg[last] - eBase;
    for (int i = t; i < cnt; i += 256)
        eidx[i] = __builtin_nontemporal_load(&es[eBase + i]);
    __syncthreads();

    int l5 = t & 31;
    int nA = node0 + (t >> 5) * 2;
    int nB = nA + 1;
    int sA = rstart[nA] - eBase, dA = rdeg[nA];
    int sB = rstart[nB] - eBase, dB = rdeg[nB];
    float2 pA = *(const float2*)&out[(size_t)nA * 64 + 2 * l5];
    float2 pB = *(const float2*)&out[(size_t)nB * 64 + 2 * l5];
    const unsigned* pbu = (const unsigned*)pb;  // row = 32 uint (64 bf16)
    float a0 = 0.f, a1 = 0.f, b0 = 0.f, b1 = 0.f;
    int eA = 0, eB = 0;
    while (eA + 4 <= dA && eB + 4 <= dB) {
        int qa0 = eidx[sA + eA + 0], qa1 = eidx[sA + eA + 1];
        int qa2 = eidx[sA + eA + 2], qa3 = eidx[sA + eA + 3];
        int qb0 = eidx[sB + eB + 0], qb1 = eidx[sB + eB + 1];
        int qb2 = eidx[sB + eB + 2], qb3 = eidx[sB + eB + 3];
        unsigned ua0 = pbu[qa0 * 32 + l5], ua1 = pbu[qa1 * 32 + l5];
        unsigned ua2 = pbu[qa2 * 32 + l5], ua3 = pbu[qa3 * 32 + l5];
        unsigned ub0 = pbu[qb0 * 32 + l5], ub1 = pbu[qb1 * 32 + l5];
        unsigned ub2 = pbu[qb2 * 32 + l5], ub3 = pbu[qb3 * 32 + l5];
        a0 += bflo(ua0) + bflo(ua1) + bflo(ua2) + bflo(ua3);
        a1 += bfhi(ua0) + bfhi(ua1) + bfhi(ua2) + bfhi(ua3);
        b0 += bflo(ub0) + bflo(ub1) + bflo(ub2) + bflo(ub3);
        b1 += bfhi(ub0) + bfhi(ub1) + bfhi(ub2) + bfhi(ub3);
        eA += 4; eB += 4;
    }
    for (; eA + 4 <= dA; eA += 4) {
        int q0 = eidx[sA + eA + 0], q1 = eidx[sA + eA + 1];
        int q2 = eidx[sA + eA + 2], q3 = eidx[sA + eA + 3];
        unsigned u0 = pbu[q0 * 32 + l5], u1 = pbu[q1 * 32 + l5];
        unsigned u2 = pbu[q2 * 32 + l5], u3 = pbu[q3 * 32 + l5];
        a0 += bflo(u0) + bflo(u1) + bflo(u2) + bflo(u3);
        a1 += bfhi(u0) + bfhi(u1) + bfhi(u2) + bfhi(u3);
    }
    for (; eA < dA; ++eA) {
        unsigned u = pbu[eidx[sA + eA] * 32 + l5];
        a0 += bflo(u); a1 += bfhi(u);
    }
    for (; eB + 4 <= dB; eB += 4) {
        int q0 = eidx[sB + eB + 0], q1 = eidx[sB + eB + 1];
        int q2 = eidx[sB + eB + 2], q3 = eidx[sB + eB + 3];
        unsigned u0 = pbu[q0 * 32 + l5], u1 = pbu[q1 * 32 + l5];
        unsigned u2 = pbu[q2 * 32 + l5], u3 = pbu[q3 * 32 + l5];
        b0 += bflo(u0) + bflo(u1) + bflo(u2) + bflo(u3);
        b1 += bfhi(u0) + bfhi(u1) + bfhi(u2) + bfhi(u3);
    }
    for (; eB < dB; ++eB) {
        unsigned u = pbu[eidx[sB + eB] * 32 + l5];
        b0 += bflo(u); b1 += bfhi(u);
    }
    float invA = 1.0f / fmaxf((float)dA, 1.0f);
    float invB = 1.0f / fmaxf((float)dB, 1.0f);
    float2 oA = {pA.x + a0 * invA, pA.y + a1 * invA};
    float2 oB = {pB.x + b0 * invB, pB.y + b1 * invB};
    *(float2*)&out[(size_t)nA * 64 + 2 * l5] = oA;
    *(float2*)&out[(size_t)nB * 64 + 2 * l5] = oB;
}

// ---------------------------------------------------------------------------
// GEMM1 fused (MFMA): h = relu(mean@W1l + x@W1r + b1); pb = bf16(h@W2l);
// out = h@W2r + b2. Weights staged in LDS (Ws = 2048 uint4 = 32 KB):
// w1l fills Ws; then w1r fills Ws; then w2l -> uint4[0,1024), w2r ->
// uint4[1024,2048) (= ushort offset 8192). Round-8 bug: w2r was staged at
// uint4[2048+] — OOB write + garbage read. Fixed.
// ---------------------------------------------------------------------------
__global__ __launch_bounds__(256) void gemm1_kernel(const ushort* __restrict__ meanb,
                                                    const ushort* __restrict__ xb,
                                                    const ushort* __restrict__ w1lp,
                                                    const ushort* __restrict__ w1rp,
                                                    const float* __restrict__ b1,
                                                    const ushort* __restrict__ w2lp,
                                                    const ushort* __restrict__ w2rp,
                                                    const float* __restrict__ b2,
                                                    ushort* __restrict__ pb,
                                                    float* __restrict__ out) {
    __shared__ ushort As[64 * 136];   // 17408 B: A tile / h tile
    __shared__ ushort Ws[16384];      // 32768 B = 2048 uint4
    int t = threadIdx.x;
    int node0 = blockIdx.x * 64;
    int w = t >> 6, l = t & 63;
    int lrow = w * 16 + (l & 15);
    int lkq = (l >> 4) * 8;
    int cq = l & 15, rq = (l >> 4) * 4;

    f32x4 acc[8];
#pragma unroll
    for (int i = 0; i < 8; ++i) acc[i] = (f32x4){0.f, 0.f, 0.f, 0.f};

    // ---- phase 1a: stage mean tile + w1l; MFMA ----
    {
        const uint4* g = (const uint4*)(meanb + (size_t)node0 * 128);
#pragma unroll
        for (int i = 0; i < 4; ++i) {
            int chunk = t + 256 * i;
            *(uint4*)&As[(chunk >> 4) * 136 + (chunk & 15) * 8] = g[chunk];
        }
        const uint4* wsrc = (const uint4*)w1lp;   // 2048 uint4 = 32 KB
#pragma unroll
        for (int i = 0; i < 8; ++i)
            ((uint4*)Ws)[t + 256 * i] = wsrc[t + 256 * i];
    }
    __syncthreads();
#pragma unroll
    for (int kt = 0; kt < 4; ++kt) {
        bf16x8 a = *(const bf16x8*)&As[lrow * 136 + kt * 32 + lkq];
        const bf16x8* bp = (const bf16x8*)Ws + (kt * 8) * 64 + l;
#pragma unroll
        for (int nt = 0; nt < 8; ++nt)
            acc[nt] = __builtin_amdgcn_mfma_f32_16x16x32_bf16(a, bp[nt * 64], acc[nt], 0, 0, 0);
    }
    __syncthreads();

    // ---- phase 1b: stage x tile + w1r; MFMA ----
    {
        const uint4* g = (const uint4*)(xb + (size_t)node0 * 128);
#pragma unroll
        for (int i = 0; i < 4; ++i) {
            int chunk = t + 256 * i;
            *(uint4*)&As[(chunk >> 4) * 136 + (chunk & 15) * 8] = g[chunk];
        }
        const uint4* wsrc = (const uint4*)w1rp;
#pragma unroll
        for (int i = 0; i < 8; ++i)
            ((uint4*)Ws)[t + 256 * i] = wsrc[t + 256 * i];
    }
    __syncthreads();
#pragma unroll
    for (int kt = 0; kt < 4; ++kt) {
        bf16x8 a = *(const bf16x8*)&As[lrow * 136 + kt * 32 + lkq];
        const bf16x8* bp = (const bf16x8*)Ws + (kt * 8) * 64 + l;
#pragma unroll
        for (int nt = 0; nt < 8; ++nt)
            acc[nt] = __builtin_amdgcn_mfma_f32_16x16x32_bf16(a, bp[nt * 64], acc[nt], 0, 0, 0);
    }
    __syncthreads();

    // ---- phase 2: h back into As; stage w2l+w2r into Ws halves ----
#pragma unroll
    for (int nt = 0; nt < 8; ++nt) {
        int n = nt * 16 + cq;
        float bias = b1[n];
#pragma unroll
        for (int r = 0; r < 4; ++r) {
            float hv = fmaxf(acc[nt][r] + bias, 0.0f);
            As[(w * 16 + rq + r) * 136 + n] = f2bf(hv);
        }
    }
    {
        const uint4* wl = (const uint4*)w2lp;  // 1024 uint4 = 16 KB
        const uint4* wr = (const uint4*)w2rp;  // 1024 uint4 = 16 KB
#pragma unroll
        for (int i = 0; i < 4; ++i) {
            int chunk = t + 256 * i;
            ((uint4*)Ws)[chunk] = wl[chunk];          // bytes [0, 16384)
            ((uint4*)Ws)[1024 + chunk] = wr[chunk];   // bytes [16384, 32768)
        }
    }
    __syncthreads();

    f32x4 acc2[4];  // h@W2l -> pb
    f32x4 acc3[4];  // h@W2r -> partial out
#pragma unroll
    for (int i = 0; i < 4; ++i) {
        acc2[i] = (f32x4){0.f, 0.f, 0.f, 0.f};
        acc3[i] = (f32x4){0.f, 0.f, 0.f, 0.f};
    }
#pragma unroll
    for (int kt = 0; kt < 4; ++kt) {
        bf16x8 a = *(const bf16x8*)&As[lrow * 136 + kt * 32 + lkq];
        const bf16x8* bpl = (const bf16x8*)Ws + (kt * 4) * 64 + l;
        const bf16x8* bpr = (const bf16x8*)(Ws + 8192) + (kt * 4) * 64 + l;  // ushort ofs 8192 = byte 16384
#pragma unroll
        for (int nt = 0; nt < 4; ++nt) {
            acc2[nt] = __builtin_amdgcn_mfma_f32_16x16x32_bf16(a, bpl[nt * 64], acc2[nt], 0, 0, 0);
            acc3[nt] = __builtin_amdgcn_mfma_f32_16x16x32_bf16(a, bpr[nt * 64], acc3[nt], 0, 0, 0);
        }
    }

    // Partial out = h@W2r + b2, straight from accumulators.
#pragma unroll
    for (int nt = 0; nt < 4; ++nt) {
        int n = nt * 16 + cq;
        float bias = b2[n];
#pragma unroll
        for (int r = 0; r < 4; ++r) {
            int row = node0 + w * 16 + rq + r;
            if (row < NN)
                out[(size_t)row * 64 + n] = acc3[nt][r] + bias;
        }
    }

    // pb = bf16(h@W2l) via LDS repack for vectorized store.
    __syncthreads();
#pragma unroll
    for (int nt = 0; nt < 4; ++nt)
#pragma unroll
        for (int r = 0; r < 4; ++r)
            As[(w * 16 + rq + r) * 136 + nt * 16 + cq] = f2bf(acc2[nt][r]);
    __syncthreads();
    {
        uint4* g = (uint4*)(pb + (size_t)node0 * 64);
#pragma unroll
        for (int i = 0; i < 2; ++i) {
            int chunk = t + 256 * i;
            if (node0 + (chunk >> 3) < NN)
                g[chunk] = *(const uint4*)&As[(chunk >> 3) * 136 + (chunk & 7) * 8];
        }
    }
}

extern "C" void kernel_launch(void* const* d_in, const int* in_sizes, int n_in,
                              void* d_out, int out_size, void* d_ws, size_t ws_size,
                              hipStream_t stream) {
    const float* x   = (const float*)d_in[0];
    const int*   ei  = (const int*)d_in[1];
    const float* W1l = (const float*)d_in[2];
    const float* W1r = (const float*)d_in[3];
    const float* b1  = (const float*)d_in[4];
    const float* W2l = (const float*)d_in[5];
    const float* W2r = (const float*)d_in[6];
    const float* b2  = (const float*)d_in[7];

    const int* src = ei;
    const int* dst = ei + NE;

    int*      ws_i   = (int*)d_ws;
    int*      cc     = ws_i + OFF_CC;
    int*      rstart = ws_i + OFF_RST;
    int*      rdeg   = ws_i + OFF_RDG;
    unsigned* stage  = (unsigned*)(ws_i + OFF_STAGE);
    ushort*   xb     = (ushort*)(ws_i + OFF_XB);
    unsigned* xf8    = (unsigned*)(ws_i + OFF_XF8);
    ushort*   pb     = (ushort*)(ws_i + OFF_XF8);   // aliases xf8 (disjoint lifetime)
    ushort*   meanb  = (ushort*)(ws_i + OFF_MEANB);
    ushort*   w1lp   = (ushort*)(ws_i + OFF_W1LP);
    ushort*   w1rp   = (ushort*)(ws_i + OFF_W1RP);
    ushort*   w2lp   = (ushort*)(ws_i + OFF_W2LP);
    ushort*   w2rp   = (ushort*)(ws_i + OFF_W2RP);

    (void)hipMemsetAsync(cc, 0, 1024 * sizeof(int), stream);

    // cpart alone (sort's only dependency), then sort co-dispatched with
    // pack+cvt so sort's latency hides under cvt's streaming pass.
    cpart_kernel<<<PBLK, 1024, 0, stream>>>(src, dst, cc, stage);
    fused2_kernel<<<F2_GRID, 1024, 0, stream>>>(
        stage, cc, rstart, rdeg, x, xb, xf8,
        W1l, W1r, W2l, W2r, w1lp, w1rp, w2lp, w2rp);

    // Layer 1: gather (LDS-staged indices) + fused GEMM (weights LDS-staged).
    agg1g_kernel<<<NN / 32, 256, 0, stream>>>(stage, rstart, rdeg, xf8, meanb);
    gemm1_kernel<<<(NN + 63) / 64, 256, 0, stream>>>(meanb, xb, w1lp, w1rp, b1,
                                                     w2lp, w2rp, b2, pb, (float*)d_out);

    // Layer 2: gather pb, mean, add into partial out.
    agg2g_kernel<<<NN / 16, 256, 0, stream>>>(stage, rstart, rdeg, pb, (float*)d_out);
}